// Round 18
// baseline (387.659 us; speedup 1.0000x reference)
//
#include <hip/hip_runtime.h>
#include <hip/hip_bf16.h>
#include <hip/hip_fp16.h>

#define NN 50000
#define NE 800000
#define SCAN_NB ((NN + 255) / 256)   // 196
#define AGG_SCALE 0.015625f          // 1/64: keeps aggH inside fp16 range
#define W_SCALE   64.0f              // folded into Wm node-block rows (exact)

typedef __attribute__((ext_vector_type(8))) short bf16x8;
typedef __attribute__((ext_vector_type(4))) float f32x4;

__device__ __forceinline__ ushort f2bf(float f) {
    __hip_bfloat16 h = __float2bfloat16(f);
    return *reinterpret_cast<ushort*>(&h);
}
__device__ __forceinline__ float bf2f(ushort u) {
    return __builtin_bit_cast(float, (uint)u << 16);
}
// split (a,b) into bf16 hi + bf16 lo planes packed as uints (exact for fp16 input)
__device__ __forceinline__ void split2(float a, float b, uint& hi, uint& lo) {
    ushort ha = f2bf(a), hb = f2bf(b);
    float fa = bf2f(ha), fb = bf2f(hb);
    ushort la = f2bf(a - fa), lb = f2bf(b - fb);
    hi = (uint)ha | ((uint)hb << 16);
    lo = (uint)la | ((uint)lb << 16);
}
__device__ __forceinline__ ushort f2h(float f) {
    __half h = __float2half(f);
    return __builtin_bit_cast(ushort, h);
}
__device__ __forceinline__ uint packh2(float a, float b) {
    return (uint)f2h(a) | ((uint)f2h(b) << 16);
}
__device__ __forceinline__ float2 h2f2(uint u) {
    __half2 h = __builtin_bit_cast(__half2, u);
    return __half22float2(h);
}

// ---------------------------------------------------------------- utilities
__global__ void zero_int_kernel(int* __restrict__ p, int n) {
    int i = blockIdx.x * blockDim.x + threadIdx.x;
    if (i < n) p[i] = 0;
}

// ---------------------------------------------------------------- CSR build
__global__ void deg_kernel(const int* __restrict__ dst, int* __restrict__ deg, int E) {
    int e = blockIdx.x * blockDim.x + threadIdx.x;
    if (e < E) atomicAdd(&deg[dst[e]], 1);
}

__global__ void scan1_kernel(const int* __restrict__ deg, int* __restrict__ pre,
                             int* __restrict__ bsum) {
    __shared__ int sm[256];
    int t = threadIdx.x;
    int i = blockIdx.x * 256 + t;
    int v = (i < NN) ? deg[i] : 0;
    sm[t] = v;
    __syncthreads();
#pragma unroll
    for (int off = 1; off < 256; off <<= 1) {
        int u = (t >= off) ? sm[t - off] : 0;
        __syncthreads();
        sm[t] += u;
        __syncthreads();
    }
    if (i < NN) pre[i] = sm[t] - v;
    if (t == 255) bsum[blockIdx.x] = sm[255];
}

__global__ void scan2_kernel(const int* __restrict__ bsum, int* __restrict__ boff) {
    __shared__ int sm[256];
    int t = threadIdx.x;
    int v = (t < SCAN_NB) ? bsum[t] : 0;
    sm[t] = v;
    __syncthreads();
#pragma unroll
    for (int off = 1; off < 256; off <<= 1) {
        int u = (t >= off) ? sm[t - off] : 0;
        __syncthreads();
        sm[t] += u;
        __syncthreads();
    }
    if (t < SCAN_NB) boff[t] = sm[t] - v;
}

__global__ void scan3_kernel(int* __restrict__ row_start, const int* __restrict__ boff,
                             int* __restrict__ cursor) {
    int i = blockIdx.x * 256 + threadIdx.x;
    if (i < NN) {
        int r = row_start[i] + boff[blockIdx.x];
        row_start[i] = r;
        cursor[i] = r;
    }
    if (i == 0) row_start[NN] = NE;
}

// fill CSR: single int2 {src, eid} scatter (8B), non-temporal (reduces L2 ping-pong)
__global__ void fill_kernel(const int* __restrict__ src, const int* __restrict__ dst,
                            int* __restrict__ cursor, int2* __restrict__ csr2, int E) {
    int e = blockIdx.x * blockDim.x + threadIdx.x;
    if (e < E) {
        int d = dst[e];
        int p = atomicAdd(&cursor[d], 1);
        long long v = (long long)(uint)src[e] | ((long long)e << 32);
        __builtin_nontemporal_store(v, reinterpret_cast<long long*>(&csr2[p]));
    }
}

// ---------------------------------------------------------------- agg_e (eid gather, fp32)
__global__ void agge_kernel(const float* __restrict__ ea, const int2* __restrict__ csr2,
                            const int* __restrict__ row_start, float* __restrict__ aggE) {
    int v = blockIdx.x * blockDim.x + threadIdx.x;
    if (v >= NN) return;
    int lo = row_start[v], hi = row_start[v + 1];
    const float4* EA = reinterpret_cast<const float4*>(ea);
    float4 a0 = {0.f,0.f,0.f,0.f}, a1 = {0.f,0.f,0.f,0.f};
    float4 b0 = {0.f,0.f,0.f,0.f}, b1 = {0.f,0.f,0.f,0.f};
    int j = lo;
    for (; j + 2 <= hi; j += 2) {
        int e0 = csr2[j].y, e1 = csr2[j + 1].y;
        float4 u0 = EA[(size_t)e0 * 2], u1 = EA[(size_t)e0 * 2 + 1];
        float4 u2 = EA[(size_t)e1 * 2], u3 = EA[(size_t)e1 * 2 + 1];
        a0.x += u0.x; a0.y += u0.y; a0.z += u0.z; a0.w += u0.w;
        a1.x += u1.x; a1.y += u1.y; a1.z += u1.z; a1.w += u1.w;
        b0.x += u2.x; b0.y += u2.y; b0.z += u2.z; b0.w += u2.w;
        b1.x += u3.x; b1.y += u3.y; b1.z += u3.z; b1.w += u3.w;
    }
    if (j < hi) {
        int e0 = csr2[j].y;
        float4 u0 = EA[(size_t)e0 * 2], u1 = EA[(size_t)e0 * 2 + 1];
        a0.x += u0.x; a0.y += u0.y; a0.z += u0.z; a0.w += u0.w;
        a1.x += u1.x; a1.y += u1.y; a1.z += u1.z; a1.w += u1.w;
    }
    a0.x += b0.x; a0.y += b0.y; a0.z += b0.z; a0.w += b0.w;
    a1.x += b1.x; a1.y += b1.y; a1.z += b1.z; a1.w += b1.w;
    float4* o = reinterpret_cast<float4*>(aggE + (size_t)v * 8);
    o[0] = a0; o[1] = a1;
}

// ---------------------------------------------------------------- agg_h layer0 (fp32 x gather, scaled fp16 out)
__global__ void aggh32_kernel(const float* __restrict__ h, const int* __restrict__ row_start,
                              const int2* __restrict__ csr2, ushort* __restrict__ aggH16) {
    int w = blockIdx.x * (blockDim.x >> 6) + (threadIdx.x >> 6);
    int lane = threadIdx.x & 63;
    if (w >= NN) return;
    int lo = row_start[w], hi = row_start[w + 1];
    int half = lane >> 5;
    int l32 = lane & 31;
    float a0 = 0.f, a1 = 0.f, a2 = 0.f, a3 = 0.f;
    int j = lo;
    while (j < hi) {
        int cnt = hi - j; if (cnt > 64) cnt = 64;
        int myidx = (lane < cnt) ? csr2[j + lane].x : 0;
        int k = 0;
        for (; k + 8 <= cnt; k += 8) {
            int s0 = __shfl(myidx, k + half);
            int s1 = __shfl(myidx, k + 2 + half);
            int s2 = __shfl(myidx, k + 4 + half);
            int s3 = __shfl(myidx, k + 6 + half);
            a0 += h[(size_t)s0 * 32 + l32];
            a1 += h[(size_t)s1 * 32 + l32];
            a2 += h[(size_t)s2 * 32 + l32];
            a3 += h[(size_t)s3 * 32 + l32];
        }
        for (; k + 2 <= cnt; k += 2) {
            int s = __shfl(myidx, k + half);
            a0 += h[(size_t)s * 32 + l32];
        }
        if (k < cnt) {
            int s = __shfl(myidx, k);
            if (half == 0) a1 += h[(size_t)s * 32 + l32];
        }
        j += cnt;
    }
    a0 = (a0 + a1) + (a2 + a3);
    a0 += __shfl_xor(a0, 32);
    a0 *= AGG_SCALE;
    float an = __shfl_down(a0, 1);
    if (lane < 32 && (lane & 1) == 0)
        reinterpret_cast<uint*>(aggH16)[(size_t)w * 16 + (lane >> 1)] = packh2(a0, an);
}

// ---------------------------------------------------------------- agg_h fp16 gather, scaled fp16 out
template <int DIN>
__global__ void aggh16_kernel(const ushort* __restrict__ h16, const int* __restrict__ row_start,
                              const int2* __restrict__ csr2, ushort* __restrict__ aggH16) {
    int w = blockIdx.x * (blockDim.x >> 6) + (threadIdx.x >> 6);
    int lane = threadIdx.x & 63;
    if (w >= NN) return;
    int lo = row_start[w], hi = row_start[w + 1];
    const uint* H = reinterpret_cast<const uint*>(h16);

    if constexpr (DIN == 128) {
        // 8 rows in flight for latency hiding
        float2 a0 = {0.f,0.f}, a1 = {0.f,0.f}, a2 = {0.f,0.f}, a3 = {0.f,0.f};
        float2 a4 = {0.f,0.f}, a5 = {0.f,0.f}, a6 = {0.f,0.f}, a7 = {0.f,0.f};
        int j = lo;
        while (j < hi) {
            int cnt = hi - j; if (cnt > 64) cnt = 64;
            int myidx = (lane < cnt) ? csr2[j + lane].x : 0;
            int k = 0;
            for (; k + 8 <= cnt; k += 8) {
                int s0 = __shfl(myidx, k);
                int s1 = __shfl(myidx, k + 1);
                int s2 = __shfl(myidx, k + 2);
                int s3 = __shfl(myidx, k + 3);
                int s4 = __shfl(myidx, k + 4);
                int s5 = __shfl(myidx, k + 5);
                int s6 = __shfl(myidx, k + 6);
                int s7 = __shfl(myidx, k + 7);
                float2 v0 = h2f2(H[(size_t)s0 * 64 + lane]);
                float2 v1 = h2f2(H[(size_t)s1 * 64 + lane]);
                float2 v2 = h2f2(H[(size_t)s2 * 64 + lane]);
                float2 v3 = h2f2(H[(size_t)s3 * 64 + lane]);
                float2 v4 = h2f2(H[(size_t)s4 * 64 + lane]);
                float2 v5 = h2f2(H[(size_t)s5 * 64 + lane]);
                float2 v6 = h2f2(H[(size_t)s6 * 64 + lane]);
                float2 v7 = h2f2(H[(size_t)s7 * 64 + lane]);
                a0.x += v0.x; a0.y += v0.y;
                a1.x += v1.x; a1.y += v1.y;
                a2.x += v2.x; a2.y += v2.y;
                a3.x += v3.x; a3.y += v3.y;
                a4.x += v4.x; a4.y += v4.y;
                a5.x += v5.x; a5.y += v5.y;
                a6.x += v6.x; a6.y += v6.y;
                a7.x += v7.x; a7.y += v7.y;
            }
            for (; k < cnt; ++k) {
                int s = __shfl(myidx, k);
                float2 v = h2f2(H[(size_t)s * 64 + lane]);
                a0.x += v.x; a0.y += v.y;
            }
            j += cnt;
        }
        a0.x += a1.x; a0.y += a1.y;
        a2.x += a3.x; a2.y += a3.y;
        a4.x += a5.x; a4.y += a5.y;
        a6.x += a7.x; a6.y += a7.y;
        a0.x += a2.x; a0.y += a2.y;
        a4.x += a6.x; a4.y += a6.y;
        a0.x += a4.x; a0.y += a4.y;
        reinterpret_cast<uint*>(aggH16)[(size_t)w * 64 + lane] =
            packh2(a0.x * AGG_SCALE, a0.y * AGG_SCALE);
    } else {  // DIN == 64
        int hf = lane >> 5, l32 = lane & 31;
        float2 a0 = {0.f,0.f}, a1 = {0.f,0.f};
        int j = lo;
        while (j < hi) {
            int cnt = hi - j; if (cnt > 64) cnt = 64;
            int myidx = (lane < cnt) ? csr2[j + lane].x : 0;
            int k = 0;
            for (; k + 4 <= cnt; k += 4) {
                int s0 = __shfl(myidx, k + hf);
                int s1 = __shfl(myidx, k + 2 + hf);
                float2 v0 = h2f2(H[(size_t)s0 * 32 + l32]);
                float2 v1 = h2f2(H[(size_t)s1 * 32 + l32]);
                a0.x += v0.x; a0.y += v0.y;
                a1.x += v1.x; a1.y += v1.y;
            }
            for (; k + 2 <= cnt; k += 2) {
                int s = __shfl(myidx, k + hf);
                float2 v = h2f2(H[(size_t)s * 32 + l32]);
                a0.x += v.x; a0.y += v.y;
            }
            if (k < cnt) {
                int s = __shfl(myidx, k);
                if (hf == 0) {
                    float2 v = h2f2(H[(size_t)s * 32 + l32]);
                    a1.x += v.x; a1.y += v.y;
                }
            }
            j += cnt;
        }
        a0.x += a1.x; a0.y += a1.y;
        a0.x += __shfl_xor(a0.x, 32);
        a0.y += __shfl_xor(a0.y, 32);
        if (lane < 32)
            reinterpret_cast<uint*>(aggH16)[(size_t)w * 32 + l32] =
                packh2(a0.x * AGG_SCALE, a0.y * AGG_SCALE);
    }
}

// ---------------------------------------------------------------- weight prep
// bf16 hi/lo W planes in MFMA-FRAGMENT-LINEAR order (proven R12).
// Node-block Wm rows (k in [DIN, 2*DIN)) pre-scaled by W_SCALE (exact pow2).
__global__ void prep_w_kernel(const float* __restrict__ Ws, const float* __restrict__ Wm,
                              ushort* __restrict__ Whi, ushort* __restrict__ Wlo,
                              int DIN, int DOUT, int KPAD) {
    int gid = blockIdx.x * blockDim.x + threadIdx.x;
    if (gid >= DOUT * KPAD) return;
    int NSUB = DOUT / 16;
    int j = gid & 7;
    int lane = (gid >> 3) & 63;
    int cs = gid >> 9;                 // c*NSUB + s
    int c = cs / NSUB, s = cs - c * NSUB;
    int col = s * 16 + (lane & 15);
    int k = c * 32 + (lane >> 4) * 8 + j;
    float v = 0.f;
    if (k < DIN) v = Ws[(size_t)k * DOUT + col];
    else if (k < 2 * DIN) v = Wm[(size_t)(k - DIN) * DOUT + col] * W_SCALE;
    else if (k < 2 * DIN + 8) v = Wm[(size_t)(k - DIN) * DOUT + col];
    ushort h = f2bf(v);
    Whi[gid] = h;
    Wlo[gid] = f2bf(v - bf2f(h));
}

// ---------------------------------------------------------------- dense MFMA v6
template <int DIN, int DOUT, bool AH16, bool FINAL>
__global__ __launch_bounds__(256) void dense_mfma(
    const float* __restrict__ hF, const ushort* __restrict__ hH,
    const ushort* __restrict__ aggH16, const float* __restrict__ aggE,
    const ushort* __restrict__ WhiF, const ushort* __restrict__ WloF,
    const float* __restrict__ bias, ushort* __restrict__ out16,
    const float* __restrict__ Wc, const float* __restrict__ bc,
    float* __restrict__ outF) {
    constexpr int HCH = DIN / 32;
    constexpr int NCH = 2 * HCH + 1;
    constexpr int NSUB = DOUT / 16;
    constexpr int SB = DOUT + 4;        // bounce stride (floats)

    __shared__ float fs[64 * SB];

    const int t = threadIdx.x;
    const int lane = t & 63, wid = t >> 6;
    const int row0 = blockIdx.x * 64;
    const int rb = wid * 16;
    const int ocol = lane & 15;
    const int rq = lane >> 4;           // k-granule for A; row-quad for C
    const int arow = row0 + rb + ocol;
    const bool rok = arow < NN;

    f32x4 acc[NSUB];
#pragma unroll
    for (int s = 0; s < NSUB; ++s) acc[s] = (f32x4){0.f, 0.f, 0.f, 0.f};

    auto loadA = [&](int c, bf16x8& ah, bf16x8& al) {
        float4 v0 = {0.f,0.f,0.f,0.f}, v1 = {0.f,0.f,0.f,0.f};
        if (rok) {
            if (c < HCH) {
                if constexpr (AH16) {
                    uint4 u = *reinterpret_cast<const uint4*>(
                        hH + (size_t)arow * DIN + c * 32 + rq * 8);
                    float2 f0 = h2f2(u.x), f1 = h2f2(u.y), f2 = h2f2(u.z), f3 = h2f2(u.w);
                    v0 = (float4){f0.x, f0.y, f1.x, f1.y};
                    v1 = (float4){f2.x, f2.y, f3.x, f3.y};
                } else {
                    const float* p = hF + (size_t)arow * DIN + c * 32 + rq * 8;
                    v0 = *reinterpret_cast<const float4*>(p);
                    v1 = *reinterpret_cast<const float4*>(p + 4);
                }
            } else if (c < 2 * HCH) {
                uint4 u = *reinterpret_cast<const uint4*>(
                    aggH16 + (size_t)arow * DIN + (c - HCH) * 32 + rq * 8);
                float2 f0 = h2f2(u.x), f1 = h2f2(u.y), f2 = h2f2(u.z), f3 = h2f2(u.w);
                v0 = (float4){f0.x, f0.y, f1.x, f1.y};
                v1 = (float4){f2.x, f2.y, f3.x, f3.y};
            } else if (rq == 0) {
                const float* p = aggE + (size_t)arow * 8;
                v0 = *reinterpret_cast<const float4*>(p);
                v1 = *reinterpret_cast<const float4*>(p + 4);
            }
        }
        uint4 hq, lq;
        split2(v0.x, v0.y, hq.x, lq.x);
        split2(v0.z, v0.w, hq.y, lq.y);
        split2(v1.x, v1.y, hq.z, lq.z);
        split2(v1.z, v1.w, hq.w, lq.w);
        ah = __builtin_bit_cast(bf16x8, hq);
        al = __builtin_bit_cast(bf16x8, lq);
    };

    bf16x8 ah, al, ah2, al2;
    loadA(0, ah, al);

    for (int c = 0; c < NCH; ++c) {
        if (c + 1 < NCH) loadA(c + 1, ah2, al2);   // prefetch flies under MFMAs
        const size_t wbase = ((size_t)(c * NSUB) * 64 + lane) * 8;
#pragma unroll
        for (int s = 0; s < NSUB; ++s) {
            bf16x8 wh = *reinterpret_cast<const bf16x8*>(WhiF + wbase + (size_t)s * 512);
            bf16x8 wl = *reinterpret_cast<const bf16x8*>(WloF + wbase + (size_t)s * 512);
            acc[s] = __builtin_amdgcn_mfma_f32_16x16x32_bf16(al, wh, acc[s], 0, 0, 0);
            acc[s] = __builtin_amdgcn_mfma_f32_16x16x32_bf16(ah, wl, acc[s], 0, 0, 0);
            acc[s] = __builtin_amdgcn_mfma_f32_16x16x32_bf16(ah, wh, acc[s], 0, 0, 0);
        }
        if (c + 1 < NCH) { ah = ah2; al = al2; }
    }

    // epilogue: bias+relu into LDS bounce, one barrier
#pragma unroll
    for (int s = 0; s < NSUB; ++s) {
        float bv = bias[s * 16 + ocol];
#pragma unroll
        for (int r = 0; r < 4; ++r) {
            float v = acc[s][r] + bv;
            v = v > 0.f ? v : 0.f;      // relu every layer (incl. feat = relu(h5))
            fs[(rb + rq * 4 + r) * SB + s * 16 + ocol] = v;
        }
    }
    __syncthreads();

    if constexpr (FINAL) {
        // fused readout: 4 threads per row, each dots 32 cols with Wc
        int r = t >> 2, q = t & 3;
        const float* p = fs + r * SB + q * 32;
        const float4* W4 = reinterpret_cast<const float4*>(Wc + q * 32);
        float s = 0.f;
#pragma unroll
        for (int i = 0; i < 8; ++i) {
            float4 wv = W4[i];
            s += p[i * 4 + 0] * wv.x + p[i * 4 + 1] * wv.y
               + p[i * 4 + 2] * wv.z + p[i * 4 + 3] * wv.w;
        }
        s += __shfl_xor(s, 1);
        s += __shfl_xor(s, 2);
        int grow = row0 + r;
        if (q == 0 && grow < NN) outF[grow] = s + bc[0];
    } else {
        for (int i = t; i < 64 * DOUT / 2; i += 256) {
            int r = i / (DOUT / 2), c2 = (i % (DOUT / 2)) * 2;
            int grow = row0 + r;
            if (grow < NN) {
                const float* p = fs + r * SB + c2;
                *reinterpret_cast<uint*>(&out16[(size_t)grow * DOUT + c2]) =
                    packh2(p[0], p[1]);
            }
        }
    }
}

// ---------------------------------------------------------------- launch
extern "C" void kernel_launch(void* const* d_in, const int* in_sizes, int n_in,
                              void* d_out, int out_size, void* d_ws, size_t ws_size,
                              hipStream_t stream) {
    const float* x   = (const float*)d_in[0];
    const float* ea  = (const float*)d_in[1];
    const int*   src = (const int*)d_in[2];
    const int*   dst = (const int*)d_in[3];
    const float* Ws[5]; const float* Wm[5]; const float* bb[5];
    for (int i = 0; i < 5; ++i) {
        Ws[i] = (const float*)d_in[4 + 3 * i];
        Wm[i] = (const float*)d_in[5 + 3 * i];
        bb[i] = (const float*)d_in[6 + 3 * i];
    }
    const float* Wc = (const float*)d_in[19];
    const float* bc = (const float*)d_in[20];
    float* out = (float*)d_out;

    size_t off = 0;
    auto alloc = [&](size_t bytes) {
        void* p = (char*)d_ws + off;
        off += (bytes + 255) & ~(size_t)255;
        return p;
    };
    ushort* aggH16  = (ushort*)alloc((size_t)NN * 128 * 2);
    float* aggE     = (float*)alloc((size_t)NN * 8 * 4);
    ushort* hA16    = (ushort*)alloc((size_t)NN * 128 * 2);
    ushort* hB16    = (ushort*)alloc((size_t)NN * 128 * 2);
    ushort* Wh0     = (ushort*)alloc((size_t)64 * 96 * 2);
    ushort* Wl0     = (ushort*)alloc((size_t)64 * 96 * 2);
    ushort* Wh1     = (ushort*)alloc((size_t)128 * 160 * 2);
    ushort* Wl1     = (ushort*)alloc((size_t)128 * 160 * 2);
    ushort* Wh2     = (ushort*)alloc((size_t)128 * 288 * 2);
    ushort* Wl2     = (ushort*)alloc((size_t)128 * 288 * 2);
    ushort* Wh3     = (ushort*)alloc((size_t)128 * 288 * 2);
    ushort* Wl3     = (ushort*)alloc((size_t)128 * 288 * 2);
    ushort* Wh4     = (ushort*)alloc((size_t)128 * 288 * 2);
    ushort* Wl4     = (ushort*)alloc((size_t)128 * 288 * 2);
    int* deg        = (int*)alloc((size_t)(NN + 1) * 4);
    int* row_start  = (int*)alloc((size_t)(NN + 1) * 4);
    int* cursor     = (int*)alloc((size_t)NN * 4);
    int2* csr2      = (int2*)alloc((size_t)NE * 8);
    int* bsum       = (int*)alloc((size_t)SCAN_NB * 4);
    int* boff       = (int*)alloc((size_t)SCAN_NB * 4);
    (void)ws_size; (void)in_sizes; (void)n_in; (void)out_size;

    // CSR build
    zero_int_kernel<<<(NN + 255) / 256, 256, 0, stream>>>(deg, NN);
    deg_kernel<<<(NE + 255) / 256, 256, 0, stream>>>(dst, deg, NE);
    scan1_kernel<<<SCAN_NB, 256, 0, stream>>>(deg, row_start, bsum);
    scan2_kernel<<<1, 256, 0, stream>>>(bsum, boff);
    scan3_kernel<<<SCAN_NB, 256, 0, stream>>>(row_start, boff, cursor);
    fill_kernel<<<(NE + 255) / 256, 256, 0, stream>>>(src, dst, cursor, csr2, NE);

    agge_kernel<<<(NN + 255) / 256, 256, 0, stream>>>(ea, csr2, row_start, aggE);

    // weight prep (bf16 hi/lo, fragment-linear, Wm node-rows pre-scaled)
    prep_w_kernel<<<(64 * 96 + 255) / 256, 256, 0, stream>>>(Ws[0], Wm[0], Wh0, Wl0, 32, 64, 96);
    prep_w_kernel<<<(128 * 160 + 255) / 256, 256, 0, stream>>>(Ws[1], Wm[1], Wh1, Wl1, 64, 128, 160);
    prep_w_kernel<<<(128 * 288 + 255) / 256, 256, 0, stream>>>(Ws[2], Wm[2], Wh2, Wl2, 128, 128, 288);
    prep_w_kernel<<<(128 * 288 + 255) / 256, 256, 0, stream>>>(Ws[3], Wm[3], Wh3, Wl3, 128, 128, 288);
    prep_w_kernel<<<(128 * 288 + 255) / 256, 256, 0, stream>>>(Ws[4], Wm[4], Wh4, Wl4, 128, 128, 288);

    const int GRID_W = (NN + 3) / 4;
    const int GRID_D = (NN + 63) / 64;

    // layer 0: 32 -> 64
    aggh32_kernel<<<GRID_W, 256, 0, stream>>>(x, row_start, csr2, aggH16);
    dense_mfma<32, 64, false, false><<<GRID_D, 256, 0, stream>>>(
        x, nullptr, aggH16, aggE, Wh0, Wl0, bb[0], hA16, nullptr, nullptr, nullptr);
    // layer 1: 64 -> 128
    aggh16_kernel<64><<<GRID_W, 256, 0, stream>>>(hA16, row_start, csr2, aggH16);
    dense_mfma<64, 128, true, false><<<GRID_D, 256, 0, stream>>>(
        nullptr, hA16, aggH16, aggE, Wh1, Wl1, bb[1], hB16, nullptr, nullptr, nullptr);
    // layer 2
    aggh16_kernel<128><<<GRID_W, 256, 0, stream>>>(hB16, row_start, csr2, aggH16);
    dense_mfma<128, 128, true, false><<<GRID_D, 256, 0, stream>>>(
        nullptr, hB16, aggH16, aggE, Wh2, Wl2, bb[2], hA16, nullptr, nullptr, nullptr);
    // layer 3
    aggh16_kernel<128><<<GRID_W, 256, 0, stream>>>(hA16, row_start, csr2, aggH16);
    dense_mfma<128, 128, true, false><<<GRID_D, 256, 0, stream>>>(
        nullptr, hA16, aggH16, aggE, Wh3, Wl3, bb[3], hB16, nullptr, nullptr, nullptr);
    // layer 4 + fused readout
    aggh16_kernel<128><<<GRID_W, 256, 0, stream>>>(hB16, row_start, csr2, aggH16);
    dense_mfma<128, 128, true, true><<<GRID_D, 256, 0, stream>>>(
        nullptr, hB16, aggH16, aggE, Wh4, Wl4, bb[4], nullptr, Wc, bc, out);
}

// Round 19
// 377.662 us; speedup vs baseline: 1.0265x; 1.0265x over previous
//
#include <hip/hip_runtime.h>
#include <hip/hip_bf16.h>
#include <hip/hip_fp16.h>

#define NN 50000
#define NE 800000
#define SCAN_NB ((NN + 255) / 256)   // 196
#define AGG_SCALE 0.015625f          // 1/64: keeps aggH inside fp16 range
#define W_SCALE   64.0f              // folded into Wm node-block rows (exact)

typedef __attribute__((ext_vector_type(8))) short bf16x8;
typedef __attribute__((ext_vector_type(4))) float f32x4;

__device__ __forceinline__ ushort f2bf(float f) {
    __hip_bfloat16 h = __float2bfloat16(f);
    return *reinterpret_cast<ushort*>(&h);
}
__device__ __forceinline__ float bf2f(ushort u) {
    return __builtin_bit_cast(float, (uint)u << 16);
}
// split (a,b) into bf16 hi + bf16 lo planes packed as uints (exact for fp16 input)
__device__ __forceinline__ void split2(float a, float b, uint& hi, uint& lo) {
    ushort ha = f2bf(a), hb = f2bf(b);
    float fa = bf2f(ha), fb = bf2f(hb);
    ushort la = f2bf(a - fa), lb = f2bf(b - fb);
    hi = (uint)ha | ((uint)hb << 16);
    lo = (uint)la | ((uint)lb << 16);
}
__device__ __forceinline__ ushort f2h(float f) {
    __half h = __float2half(f);
    return __builtin_bit_cast(ushort, h);
}
__device__ __forceinline__ uint packh2(float a, float b) {
    return (uint)f2h(a) | ((uint)f2h(b) << 16);
}
__device__ __forceinline__ float2 h2f2(uint u) {
    __half2 h = __builtin_bit_cast(__half2, u);
    return __half22float2(h);
}

// ---------------------------------------------------------------- utilities
__global__ void zero_int_kernel(int* __restrict__ p, int n) {
    int i = blockIdx.x * blockDim.x + threadIdx.x;
    if (i < n) p[i] = 0;
}

// ---------------------------------------------------------------- CSR build
__global__ void deg_kernel(const int* __restrict__ dst, int* __restrict__ deg, int E) {
    int e = blockIdx.x * blockDim.x + threadIdx.x;
    if (e < E) atomicAdd(&deg[dst[e]], 1);
}

__global__ void scan1_kernel(const int* __restrict__ deg, int* __restrict__ pre,
                             int* __restrict__ bsum) {
    __shared__ int sm[256];
    int t = threadIdx.x;
    int i = blockIdx.x * 256 + t;
    int v = (i < NN) ? deg[i] : 0;
    sm[t] = v;
    __syncthreads();
#pragma unroll
    for (int off = 1; off < 256; off <<= 1) {
        int u = (t >= off) ? sm[t - off] : 0;
        __syncthreads();
        sm[t] += u;
        __syncthreads();
    }
    if (i < NN) pre[i] = sm[t] - v;
    if (t == 255) bsum[blockIdx.x] = sm[255];
}

// fused scan2+scan3: each block computes its own bsum prefix (196 values)
__global__ void scan23_kernel(const int* __restrict__ bsum, int* __restrict__ row_start,
                              int* __restrict__ cursor) {
    __shared__ int sm[256];
    int t = threadIdx.x;
    sm[t] = (t < (int)blockIdx.x) ? bsum[t] : 0;   // blockIdx.x < 256
    __syncthreads();
#pragma unroll
    for (int off = 128; off; off >>= 1) {
        if (t < off) sm[t] += sm[t + off];
        __syncthreads();
    }
    int boff = sm[0];
    int i = blockIdx.x * 256 + t;
    if (i < NN) {
        int r = row_start[i] + boff;
        row_start[i] = r;
        cursor[i] = r;
    }
    if (i == 0) row_start[NN] = NE;
}

// fill CSR: single int2 {src, eid} scatter (8B)
__global__ void fill_kernel(const int* __restrict__ src, const int* __restrict__ dst,
                            int* __restrict__ cursor, int2* __restrict__ csr2, int E) {
    int e = blockIdx.x * blockDim.x + threadIdx.x;
    if (e < E) {
        int d = dst[e];
        int p = atomicAdd(&cursor[d], 1);
        csr2[p] = make_int2(src[e], e);
    }
}

// ---------------------------------------------------------------- agg_e (eid gather, fp32)
__global__ void agge_kernel(const float* __restrict__ ea, const int2* __restrict__ csr2,
                            const int* __restrict__ row_start, float* __restrict__ aggE) {
    int v = blockIdx.x * blockDim.x + threadIdx.x;
    if (v >= NN) return;
    int lo = row_start[v], hi = row_start[v + 1];
    const float4* EA = reinterpret_cast<const float4*>(ea);
    float4 a0 = {0.f,0.f,0.f,0.f}, a1 = {0.f,0.f,0.f,0.f};
    float4 b0 = {0.f,0.f,0.f,0.f}, b1 = {0.f,0.f,0.f,0.f};
    int j = lo;
    for (; j + 2 <= hi; j += 2) {
        int e0 = csr2[j].y, e1 = csr2[j + 1].y;
        float4 u0 = EA[(size_t)e0 * 2], u1 = EA[(size_t)e0 * 2 + 1];
        float4 u2 = EA[(size_t)e1 * 2], u3 = EA[(size_t)e1 * 2 + 1];
        a0.x += u0.x; a0.y += u0.y; a0.z += u0.z; a0.w += u0.w;
        a1.x += u1.x; a1.y += u1.y; a1.z += u1.z; a1.w += u1.w;
        b0.x += u2.x; b0.y += u2.y; b0.z += u2.z; b0.w += u2.w;
        b1.x += u3.x; b1.y += u3.y; b1.z += u3.z; b1.w += u3.w;
    }
    if (j < hi) {
        int e0 = csr2[j].y;
        float4 u0 = EA[(size_t)e0 * 2], u1 = EA[(size_t)e0 * 2 + 1];
        a0.x += u0.x; a0.y += u0.y; a0.z += u0.z; a0.w += u0.w;
        a1.x += u1.x; a1.y += u1.y; a1.z += u1.z; a1.w += u1.w;
    }
    a0.x += b0.x; a0.y += b0.y; a0.z += b0.z; a0.w += b0.w;
    a1.x += b1.x; a1.y += b1.y; a1.z += b1.z; a1.w += b1.w;
    float4* o = reinterpret_cast<float4*>(aggE + (size_t)v * 8);
    o[0] = a0; o[1] = a1;
}

// ---------------------------------------------------------------- agg_h layer0 (fp32 x gather, scaled fp16 out)
__global__ void aggh32_kernel(const float* __restrict__ h, const int* __restrict__ row_start,
                              const int2* __restrict__ csr2, ushort* __restrict__ aggH16) {
    int w = blockIdx.x * (blockDim.x >> 6) + (threadIdx.x >> 6);
    int lane = threadIdx.x & 63;
    if (w >= NN) return;
    int lo = row_start[w], hi = row_start[w + 1];
    int half = lane >> 5;
    int l32 = lane & 31;
    float a0 = 0.f, a1 = 0.f, a2 = 0.f, a3 = 0.f;
    int j = lo;
    while (j < hi) {
        int cnt = hi - j; if (cnt > 64) cnt = 64;
        int myidx = (lane < cnt) ? csr2[j + lane].x : 0;
        int k = 0;
        for (; k + 8 <= cnt; k += 8) {
            int s0 = __shfl(myidx, k + half);
            int s1 = __shfl(myidx, k + 2 + half);
            int s2 = __shfl(myidx, k + 4 + half);
            int s3 = __shfl(myidx, k + 6 + half);
            a0 += h[(size_t)s0 * 32 + l32];
            a1 += h[(size_t)s1 * 32 + l32];
            a2 += h[(size_t)s2 * 32 + l32];
            a3 += h[(size_t)s3 * 32 + l32];
        }
        for (; k + 2 <= cnt; k += 2) {
            int s = __shfl(myidx, k + half);
            a0 += h[(size_t)s * 32 + l32];
        }
        if (k < cnt) {
            int s = __shfl(myidx, k);
            if (half == 0) a1 += h[(size_t)s * 32 + l32];
        }
        j += cnt;
    }
    a0 = (a0 + a1) + (a2 + a3);
    a0 += __shfl_xor(a0, 32);
    a0 *= AGG_SCALE;
    float an = __shfl_down(a0, 1);
    if (lane < 32 && (lane & 1) == 0)
        reinterpret_cast<uint*>(aggH16)[(size_t)w * 16 + (lane >> 1)] = packh2(a0, an);
}

// ---------------------------------------------------------------- agg_h fp16 gather, scaled fp16 out
template <int DIN>
__global__ void aggh16_kernel(const ushort* __restrict__ h16, const int* __restrict__ row_start,
                              const int2* __restrict__ csr2, ushort* __restrict__ aggH16) {
    int w = blockIdx.x * (blockDim.x >> 6) + (threadIdx.x >> 6);
    int lane = threadIdx.x & 63;
    if (w >= NN) return;
    int lo = row_start[w], hi = row_start[w + 1];
    const uint* H = reinterpret_cast<const uint*>(h16);

    if constexpr (DIN == 128) {
        float2 a0 = {0.f,0.f}, a1 = {0.f,0.f}, a2 = {0.f,0.f}, a3 = {0.f,0.f};
        int j = lo;
        while (j < hi) {
            int cnt = hi - j; if (cnt > 64) cnt = 64;
            int myidx = (lane < cnt) ? csr2[j + lane].x : 0;
            int k = 0;
            for (; k + 4 <= cnt; k += 4) {
                int s0 = __shfl(myidx, k);
                int s1 = __shfl(myidx, k + 1);
                int s2 = __shfl(myidx, k + 2);
                int s3 = __shfl(myidx, k + 3);
                float2 v0 = h2f2(H[(size_t)s0 * 64 + lane]);
                float2 v1 = h2f2(H[(size_t)s1 * 64 + lane]);
                float2 v2 = h2f2(H[(size_t)s2 * 64 + lane]);
                float2 v3 = h2f2(H[(size_t)s3 * 64 + lane]);
                a0.x += v0.x; a0.y += v0.y;
                a1.x += v1.x; a1.y += v1.y;
                a2.x += v2.x; a2.y += v2.y;
                a3.x += v3.x; a3.y += v3.y;
            }
            for (; k < cnt; ++k) {
                int s = __shfl(myidx, k);
                float2 v = h2f2(H[(size_t)s * 64 + lane]);
                a0.x += v.x; a0.y += v.y;
            }
            j += cnt;
        }
        a0.x += a1.x; a0.y += a1.y;
        a2.x += a3.x; a2.y += a3.y;
        a0.x += a2.x; a0.y += a2.y;
        reinterpret_cast<uint*>(aggH16)[(size_t)w * 64 + lane] =
            packh2(a0.x * AGG_SCALE, a0.y * AGG_SCALE);
    } else {  // DIN == 64
        int hf = lane >> 5, l32 = lane & 31;
        float2 a0 = {0.f,0.f}, a1 = {0.f,0.f};
        int j = lo;
        while (j < hi) {
            int cnt = hi - j; if (cnt > 64) cnt = 64;
            int myidx = (lane < cnt) ? csr2[j + lane].x : 0;
            int k = 0;
            for (; k + 4 <= cnt; k += 4) {
                int s0 = __shfl(myidx, k + hf);
                int s1 = __shfl(myidx, k + 2 + hf);
                float2 v0 = h2f2(H[(size_t)s0 * 32 + l32]);
                float2 v1 = h2f2(H[(size_t)s1 * 32 + l32]);
                a0.x += v0.x; a0.y += v0.y;
                a1.x += v1.x; a1.y += v1.y;
            }
            for (; k + 2 <= cnt; k += 2) {
                int s = __shfl(myidx, k + hf);
                float2 v = h2f2(H[(size_t)s * 32 + l32]);
                a0.x += v.x; a0.y += v.y;
            }
            if (k < cnt) {
                int s = __shfl(myidx, k);
                if (hf == 0) {
                    float2 v = h2f2(H[(size_t)s * 32 + l32]);
                    a1.x += v.x; a1.y += v.y;
                }
            }
            j += cnt;
        }
        a0.x += a1.x; a0.y += a1.y;
        a0.x += __shfl_xor(a0.x, 32);
        a0.y += __shfl_xor(a0.y, 32);
        if (lane < 32)
            reinterpret_cast<uint*>(aggH16)[(size_t)w * 32 + l32] =
                packh2(a0.x * AGG_SCALE, a0.y * AGG_SCALE);
    }
}

// ---------------------------------------------------------------- weight prep (ALL layers, one dispatch)
// bf16 hi/lo W planes in MFMA-FRAGMENT-LINEAR order (proven R12); Wm node-rows
// pre-scaled by W_SCALE (exact pow2). gid ranges select the layer.
#define PW_N0 6144       // 64*96
#define PW_N1 20480      // 128*160
#define PW_N2 36864      // 128*288
#define PW_TOTAL (PW_N0 + PW_N1 + 3 * PW_N2)   // 137216
__global__ void prep_w_all(
    const float* __restrict__ Ws0, const float* __restrict__ Wm0, ushort* __restrict__ Wh0, ushort* __restrict__ Wl0,
    const float* __restrict__ Ws1, const float* __restrict__ Wm1, ushort* __restrict__ Wh1, ushort* __restrict__ Wl1,
    const float* __restrict__ Ws2, const float* __restrict__ Wm2, ushort* __restrict__ Wh2, ushort* __restrict__ Wl2,
    const float* __restrict__ Ws3, const float* __restrict__ Wm3, ushort* __restrict__ Wh3, ushort* __restrict__ Wl3,
    const float* __restrict__ Ws4, const float* __restrict__ Wm4, ushort* __restrict__ Wh4, ushort* __restrict__ Wl4) {
    int gid = blockIdx.x * blockDim.x + threadIdx.x;
    if (gid >= PW_TOTAL) return;
    const float *Ws, *Wm; ushort *Whi, *Wlo;
    int DIN, DOUT, lg;
    if (gid < PW_N0) {
        Ws = Ws0; Wm = Wm0; Whi = Wh0; Wlo = Wl0; DIN = 32;  DOUT = 64;  lg = gid;
    } else if (gid < PW_N0 + PW_N1) {
        Ws = Ws1; Wm = Wm1; Whi = Wh1; Wlo = Wl1; DIN = 64;  DOUT = 128; lg = gid - PW_N0;
    } else if (gid < PW_N0 + PW_N1 + PW_N2) {
        Ws = Ws2; Wm = Wm2; Whi = Wh2; Wlo = Wl2; DIN = 128; DOUT = 128; lg = gid - PW_N0 - PW_N1;
    } else if (gid < PW_N0 + PW_N1 + 2 * PW_N2) {
        Ws = Ws3; Wm = Wm3; Whi = Wh3; Wlo = Wl3; DIN = 128; DOUT = 128; lg = gid - PW_N0 - PW_N1 - PW_N2;
    } else {
        Ws = Ws4; Wm = Wm4; Whi = Wh4; Wlo = Wl4; DIN = 128; DOUT = 128; lg = gid - PW_N0 - PW_N1 - 2 * PW_N2;
    }
    int NSUB = DOUT / 16;
    int j = lg & 7;
    int lane = (lg >> 3) & 63;
    int cs = lg >> 9;
    int c = cs / NSUB, s = cs - c * NSUB;
    int col = s * 16 + (lane & 15);
    int k = c * 32 + (lane >> 4) * 8 + j;
    float v = 0.f;
    if (k < DIN) v = Ws[(size_t)k * DOUT + col];
    else if (k < 2 * DIN) v = Wm[(size_t)(k - DIN) * DOUT + col] * W_SCALE;
    else if (k < 2 * DIN + 8) v = Wm[(size_t)(k - DIN) * DOUT + col];
    ushort h = f2bf(v);
    Whi[lg] = h;
    Wlo[lg] = f2bf(v - bf2f(h));
}

// ---------------------------------------------------------------- dense MFMA v6
template <int DIN, int DOUT, bool AH16, bool FINAL>
__global__ __launch_bounds__(256) void dense_mfma(
    const float* __restrict__ hF, const ushort* __restrict__ hH,
    const ushort* __restrict__ aggH16, const float* __restrict__ aggE,
    const ushort* __restrict__ WhiF, const ushort* __restrict__ WloF,
    const float* __restrict__ bias, ushort* __restrict__ out16,
    const float* __restrict__ Wc, const float* __restrict__ bc,
    float* __restrict__ outF) {
    constexpr int HCH = DIN / 32;
    constexpr int NCH = 2 * HCH + 1;
    constexpr int NSUB = DOUT / 16;
    constexpr int SB = DOUT + 4;        // bounce stride (floats)

    __shared__ float fs[64 * SB];

    const int t = threadIdx.x;
    const int lane = t & 63, wid = t >> 6;
    const int row0 = blockIdx.x * 64;
    const int rb = wid * 16;
    const int ocol = lane & 15;
    const int rq = lane >> 4;           // k-granule for A; row-quad for C
    const int arow = row0 + rb + ocol;
    const bool rok = arow < NN;

    f32x4 acc[NSUB];
#pragma unroll
    for (int s = 0; s < NSUB; ++s) acc[s] = (f32x4){0.f, 0.f, 0.f, 0.f};

    auto loadA = [&](int c, bf16x8& ah, bf16x8& al) {
        float4 v0 = {0.f,0.f,0.f,0.f}, v1 = {0.f,0.f,0.f,0.f};
        if (rok) {
            if (c < HCH) {
                if constexpr (AH16) {
                    uint4 u = *reinterpret_cast<const uint4*>(
                        hH + (size_t)arow * DIN + c * 32 + rq * 8);
                    float2 f0 = h2f2(u.x), f1 = h2f2(u.y), f2 = h2f2(u.z), f3 = h2f2(u.w);
                    v0 = (float4){f0.x, f0.y, f1.x, f1.y};
                    v1 = (float4){f2.x, f2.y, f3.x, f3.y};
                } else {
                    const float* p = hF + (size_t)arow * DIN + c * 32 + rq * 8;
                    v0 = *reinterpret_cast<const float4*>(p);
                    v1 = *reinterpret_cast<const float4*>(p + 4);
                }
            } else if (c < 2 * HCH) {
                uint4 u = *reinterpret_cast<const uint4*>(
                    aggH16 + (size_t)arow * DIN + (c - HCH) * 32 + rq * 8);
                float2 f0 = h2f2(u.x), f1 = h2f2(u.y), f2 = h2f2(u.z), f3 = h2f2(u.w);
                v0 = (float4){f0.x, f0.y, f1.x, f1.y};
                v1 = (float4){f2.x, f2.y, f3.x, f3.y};
            } else if (rq == 0) {
                const float* p = aggE + (size_t)arow * 8;
                v0 = *reinterpret_cast<const float4*>(p);
                v1 = *reinterpret_cast<const float4*>(p + 4);
            }
        }
        uint4 hq, lq;
        split2(v0.x, v0.y, hq.x, lq.x);
        split2(v0.z, v0.w, hq.y, lq.y);
        split2(v1.x, v1.y, hq.z, lq.z);
        split2(v1.z, v1.w, hq.w, lq.w);
        ah = __builtin_bit_cast(bf16x8, hq);
        al = __builtin_bit_cast(bf16x8, lq);
    };

    bf16x8 ah, al, ah2, al2;
    loadA(0, ah, al);

    for (int c = 0; c < NCH; ++c) {
        if (c + 1 < NCH) loadA(c + 1, ah2, al2);   // prefetch flies under MFMAs
        const size_t wbase = ((size_t)(c * NSUB) * 64 + lane) * 8;
#pragma unroll
        for (int s = 0; s < NSUB; ++s) {
            bf16x8 wh = *reinterpret_cast<const bf16x8*>(WhiF + wbase + (size_t)s * 512);
            bf16x8 wl = *reinterpret_cast<const bf16x8*>(WloF + wbase + (size_t)s * 512);
            acc[s] = __builtin_amdgcn_mfma_f32_16x16x32_bf16(al, wh, acc[s], 0, 0, 0);
            acc[s] = __builtin_amdgcn_mfma_f32_16x16x32_bf16(ah, wl, acc[s], 0, 0, 0);
            acc[s] = __builtin_amdgcn_mfma_f32_16x16x32_bf16(ah, wh, acc[s], 0, 0, 0);
        }
        if (c + 1 < NCH) { ah = ah2; al = al2; }
    }

    // epilogue: bias+relu into LDS bounce, one barrier
#pragma unroll
    for (int s = 0; s < NSUB; ++s) {
        float bv = bias[s * 16 + ocol];
#pragma unroll
        for (int r = 0; r < 4; ++r) {
            float v = acc[s][r] + bv;
            v = v > 0.f ? v : 0.f;      // relu every layer (incl. feat = relu(h5))
            fs[(rb + rq * 4 + r) * SB + s * 16 + ocol] = v;
        }
    }
    __syncthreads();

    if constexpr (FINAL) {
        // fused readout: 4 threads per row, each dots 32 cols with Wc
        int r = t >> 2, q = t & 3;
        const float* p = fs + r * SB + q * 32;
        const float4* W4 = reinterpret_cast<const float4*>(Wc + q * 32);
        float s = 0.f;
#pragma unroll
        for (int i = 0; i < 8; ++i) {
            float4 wv = W4[i];
            s += p[i * 4 + 0] * wv.x + p[i * 4 + 1] * wv.y
               + p[i * 4 + 2] * wv.z + p[i * 4 + 3] * wv.w;
        }
        s += __shfl_xor(s, 1);
        s += __shfl_xor(s, 2);
        int grow = row0 + r;
        if (q == 0 && grow < NN) outF[grow] = s + bc[0];
    } else {
        for (int i = t; i < 64 * DOUT / 2; i += 256) {
            int r = i / (DOUT / 2), c2 = (i % (DOUT / 2)) * 2;
            int grow = row0 + r;
            if (grow < NN) {
                const float* p = fs + r * SB + c2;
                *reinterpret_cast<uint*>(&out16[(size_t)grow * DOUT + c2]) =
                    packh2(p[0], p[1]);
            }
        }
    }
}

// ---------------------------------------------------------------- launch
extern "C" void kernel_launch(void* const* d_in, const int* in_sizes, int n_in,
                              void* d_out, int out_size, void* d_ws, size_t ws_size,
                              hipStream_t stream) {
    const float* x   = (const float*)d_in[0];
    const float* ea  = (const float*)d_in[1];
    const int*   src = (const int*)d_in[2];
    const int*   dst = (const int*)d_in[3];
    const float* Ws[5]; const float* Wm[5]; const float* bb[5];
    for (int i = 0; i < 5; ++i) {
        Ws[i] = (const float*)d_in[4 + 3 * i];
        Wm[i] = (const float*)d_in[5 + 3 * i];
        bb[i] = (const float*)d_in[6 + 3 * i];
    }
    const float* Wc = (const float*)d_in[19];
    const float* bc = (const float*)d_in[20];
    float* out = (float*)d_out;

    size_t off = 0;
    auto alloc = [&](size_t bytes) {
        void* p = (char*)d_ws + off;
        off += (bytes + 255) & ~(size_t)255;
        return p;
    };
    ushort* aggH16  = (ushort*)alloc((size_t)NN * 128 * 2);
    float* aggE     = (float*)alloc((size_t)NN * 8 * 4);
    ushort* hA16    = (ushort*)alloc((size_t)NN * 128 * 2);
    ushort* hB16    = (ushort*)alloc((size_t)NN * 128 * 2);
    ushort* Wh0     = (ushort*)alloc((size_t)64 * 96 * 2);
    ushort* Wl0     = (ushort*)alloc((size_t)64 * 96 * 2);
    ushort* Wh1     = (ushort*)alloc((size_t)128 * 160 * 2);
    ushort* Wl1     = (ushort*)alloc((size_t)128 * 160 * 2);
    ushort* Wh2     = (ushort*)alloc((size_t)128 * 288 * 2);
    ushort* Wl2     = (ushort*)alloc((size_t)128 * 288 * 2);
    ushort* Wh3     = (ushort*)alloc((size_t)128 * 288 * 2);
    ushort* Wl3     = (ushort*)alloc((size_t)128 * 288 * 2);
    ushort* Wh4     = (ushort*)alloc((size_t)128 * 288 * 2);
    ushort* Wl4     = (ushort*)alloc((size_t)128 * 288 * 2);
    int* deg        = (int*)alloc((size_t)(NN + 1) * 4);
    int* row_start  = (int*)alloc((size_t)(NN + 1) * 4);
    int* cursor     = (int*)alloc((size_t)NN * 4);
    int2* csr2      = (int2*)alloc((size_t)NE * 8);
    int* bsum       = (int*)alloc((size_t)SCAN_NB * 4);
    (void)ws_size; (void)in_sizes; (void)n_in; (void)out_size;

    // CSR build
    zero_int_kernel<<<(NN + 255) / 256, 256, 0, stream>>>(deg, NN);
    deg_kernel<<<(NE + 255) / 256, 256, 0, stream>>>(dst, deg, NE);
    scan1_kernel<<<SCAN_NB, 256, 0, stream>>>(deg, row_start, bsum);
    scan23_kernel<<<SCAN_NB, 256, 0, stream>>>(bsum, row_start, cursor);
    fill_kernel<<<(NE + 255) / 256, 256, 0, stream>>>(src, dst, cursor, csr2, NE);

    agge_kernel<<<(NN + 255) / 256, 256, 0, stream>>>(ea, csr2, row_start, aggE);

    // weight prep (all 5 layers in ONE dispatch)
    prep_w_all<<<(PW_TOTAL + 255) / 256, 256, 0, stream>>>(
        Ws[0], Wm[0], Wh0, Wl0, Ws[1], Wm[1], Wh1, Wl1, Ws[2], Wm[2], Wh2, Wl2,
        Ws[3], Wm[3], Wh3, Wl3, Ws[4], Wm[4], Wh4, Wl4);

    const int GRID_W = (NN + 3) / 4;
    const int GRID_D = (NN + 63) / 64;

    // layer 0: 32 -> 64
    aggh32_kernel<<<GRID_W, 256, 0, stream>>>(x, row_start, csr2, aggH16);
    dense_mfma<32, 64, false, false><<<GRID_D, 256, 0, stream>>>(
        x, nullptr, aggH16, aggE, Wh0, Wl0, bb[0], hA16, nullptr, nullptr, nullptr);
    // layer 1: 64 -> 128
    aggh16_kernel<64><<<GRID_W, 256, 0, stream>>>(hA16, row_start, csr2, aggH16);
    dense_mfma<64, 128, true, false><<<GRID_D, 256, 0, stream>>>(
        nullptr, hA16, aggH16, aggE, Wh1, Wl1, bb[1], hB16, nullptr, nullptr, nullptr);
    // layer 2
    aggh16_kernel<128><<<GRID_W, 256, 0, stream>>>(hB16, row_start, csr2, aggH16);
    dense_mfma<128, 128, true, false><<<GRID_D, 256, 0, stream>>>(
        nullptr, hB16, aggH16, aggE, Wh2, Wl2, bb[2], hA16, nullptr, nullptr, nullptr);
    // layer 3
    aggh16_kernel<128><<<GRID_W, 256, 0, stream>>>(hA16, row_start, csr2, aggH16);
    dense_mfma<128, 128, true, false><<<GRID_D, 256, 0, stream>>>(
        nullptr, hA16, aggH16, aggE, Wh3, Wl3, bb[3], hB16, nullptr, nullptr, nullptr);
    // layer 4 + fused readout
    aggh16_kernel<128><<<GRID_W, 256, 0, stream>>>(hB16, row_start, csr2, aggH16);
    dense_mfma<128, 128, true, true><<<GRID_D, 256, 0, stream>>>(
        nullptr, hB16, aggH16, aggE, Wh4, Wl4, bb[4], nullptr, Wc, bc, out);
}

// Round 20
// 331.640 us; speedup vs baseline: 1.1689x; 1.1388x over previous
//
#include <hip/hip_runtime.h>
#include <hip/hip_bf16.h>
#include <hip/hip_fp16.h>

#define NN 50000
#define NE 800000
#define SCAN_NB ((NN + 255) / 256)   // 196
#define AGG_SCALE 0.015625f          // 1/64: keeps aggH inside fp16 range
#define W_SCALE   64.0f              // folded into Wm node-block rows (exact)

typedef __attribute__((ext_vector_type(8))) _Float16 f16x8;
typedef __attribute__((ext_vector_type(4))) float f32x4;

__device__ __forceinline__ ushort f2h(float f) {
    __half h = __float2half(f);
    return __builtin_bit_cast(ushort, h);
}
__device__ __forceinline__ uint packh2(float a, float b) {
    return (uint)f2h(a) | ((uint)f2h(b) << 16);
}
__device__ __forceinline__ float2 h2f2(uint u) {
    __half2 h = __builtin_bit_cast(__half2, u);
    return __half22float2(h);
}

// ---------------------------------------------------------------- utilities
__global__ void zero_int_kernel(int* __restrict__ p, int n) {
    int i = blockIdx.x * blockDim.x + threadIdx.x;
    if (i < n) p[i] = 0;
}

// ---------------------------------------------------------------- CSR build
__global__ void deg_kernel(const int* __restrict__ dst, int* __restrict__ deg, int E) {
    int e = blockIdx.x * blockDim.x + threadIdx.x;
    if (e < E) atomicAdd(&deg[dst[e]], 1);
}

__global__ void scan1_kernel(const int* __restrict__ deg, int* __restrict__ pre,
                             int* __restrict__ bsum) {
    __shared__ int sm[256];
    int t = threadIdx.x;
    int i = blockIdx.x * 256 + t;
    int v = (i < NN) ? deg[i] : 0;
    sm[t] = v;
    __syncthreads();
#pragma unroll
    for (int off = 1; off < 256; off <<= 1) {
        int u = (t >= off) ? sm[t - off] : 0;
        __syncthreads();
        sm[t] += u;
        __syncthreads();
    }
    if (i < NN) pre[i] = sm[t] - v;
    if (t == 255) bsum[blockIdx.x] = sm[255];
}

// fused scan2+scan3: each block computes its own bsum prefix (196 values)
__global__ void scan23_kernel(const int* __restrict__ bsum, int* __restrict__ row_start,
                              int* __restrict__ cursor) {
    __shared__ int sm[256];
    int t = threadIdx.x;
    sm[t] = (t < (int)blockIdx.x) ? bsum[t] : 0;   // blockIdx.x < 256
    __syncthreads();
#pragma unroll
    for (int off = 128; off; off >>= 1) {
        if (t < off) sm[t] += sm[t + off];
        __syncthreads();
    }
    int boff = sm[0];
    int i = blockIdx.x * 256 + t;
    if (i < NN) {
        int r = row_start[i] + boff;
        row_start[i] = r;
        cursor[i] = r;
    }
    if (i == 0) row_start[NN] = NE;
}

// fill CSR: single int2 {src, eid} scatter (8B)
__global__ void fill_kernel(const int* __restrict__ src, const int* __restrict__ dst,
                            int* __restrict__ cursor, int2* __restrict__ csr2, int E) {
    int e = blockIdx.x * blockDim.x + threadIdx.x;
    if (e < E) {
        int d = dst[e];
        int p = atomicAdd(&cursor[d], 1);
        csr2[p] = make_int2(src[e], e);
    }
}

// ---------------------------------------------------------------- agg_e (eid gather, fp32)
__global__ void agge_kernel(const float* __restrict__ ea, const int2* __restrict__ csr2,
                            const int* __restrict__ row_start, float* __restrict__ aggE) {
    int v = blockIdx.x * blockDim.x + threadIdx.x;
    if (v >= NN) return;
    int lo = row_start[v], hi = row_start[v + 1];
    const float4* EA = reinterpret_cast<const float4*>(ea);
    float4 a0 = {0.f,0.f,0.f,0.f}, a1 = {0.f,0.f,0.f,0.f};
    float4 b0 = {0.f,0.f,0.f,0.f}, b1 = {0.f,0.f,0.f,0.f};
    int j = lo;
    for (; j + 2 <= hi; j += 2) {
        int e0 = csr2[j].y, e1 = csr2[j + 1].y;
        float4 u0 = EA[(size_t)e0 * 2], u1 = EA[(size_t)e0 * 2 + 1];
        float4 u2 = EA[(size_t)e1 * 2], u3 = EA[(size_t)e1 * 2 + 1];
        a0.x += u0.x; a0.y += u0.y; a0.z += u0.z; a0.w += u0.w;
        a1.x += u1.x; a1.y += u1.y; a1.z += u1.z; a1.w += u1.w;
        b0.x += u2.x; b0.y += u2.y; b0.z += u2.z; b0.w += u2.w;
        b1.x += u3.x; b1.y += u3.y; b1.z += u3.z; b1.w += u3.w;
    }
    if (j < hi) {
        int e0 = csr2[j].y;
        float4 u0 = EA[(size_t)e0 * 2], u1 = EA[(size_t)e0 * 2 + 1];
        a0.x += u0.x; a0.y += u0.y; a0.z += u0.z; a0.w += u0.w;
        a1.x += u1.x; a1.y += u1.y; a1.z += u1.z; a1.w += u1.w;
    }
    a0.x += b0.x; a0.y += b0.y; a0.z += b0.z; a0.w += b0.w;
    a1.x += b1.x; a1.y += b1.y; a1.z += b1.z; a1.w += b1.w;
    float4* o = reinterpret_cast<float4*>(aggE + (size_t)v * 8);
    o[0] = a0; o[1] = a1;
}

// ---------------------------------------------------------------- agg_h layer0 (fp32 x gather, scaled fp16 out)
__global__ void aggh32_kernel(const float* __restrict__ h, const int* __restrict__ row_start,
                              const int2* __restrict__ csr2, ushort* __restrict__ aggH16) {
    int w = blockIdx.x * (blockDim.x >> 6) + (threadIdx.x >> 6);
    int lane = threadIdx.x & 63;
    if (w >= NN) return;
    int lo = row_start[w], hi = row_start[w + 1];
    int half = lane >> 5;
    int l32 = lane & 31;
    float a0 = 0.f, a1 = 0.f, a2 = 0.f, a3 = 0.f;
    int j = lo;
    while (j < hi) {
        int cnt = hi - j; if (cnt > 64) cnt = 64;
        int myidx = (lane < cnt) ? csr2[j + lane].x : 0;
        int k = 0;
        for (; k + 8 <= cnt; k += 8) {
            int s0 = __shfl(myidx, k + half);
            int s1 = __shfl(myidx, k + 2 + half);
            int s2 = __shfl(myidx, k + 4 + half);
            int s3 = __shfl(myidx, k + 6 + half);
            a0 += h[(size_t)s0 * 32 + l32];
            a1 += h[(size_t)s1 * 32 + l32];
            a2 += h[(size_t)s2 * 32 + l32];
            a3 += h[(size_t)s3 * 32 + l32];
        }
        for (; k + 2 <= cnt; k += 2) {
            int s = __shfl(myidx, k + half);
            a0 += h[(size_t)s * 32 + l32];
        }
        if (k < cnt) {
            int s = __shfl(myidx, k);
            if (half == 0) a1 += h[(size_t)s * 32 + l32];
        }
        j += cnt;
    }
    a0 = (a0 + a1) + (a2 + a3);
    a0 += __shfl_xor(a0, 32);
    a0 *= AGG_SCALE;
    float an = __shfl_down(a0, 1);
    if (lane < 32 && (lane & 1) == 0)
        reinterpret_cast<uint*>(aggH16)[(size_t)w * 16 + (lane >> 1)] = packh2(a0, an);
}

// ---------------------------------------------------------------- agg_h fp16 gather, scaled fp16 out
template <int DIN>
__global__ void aggh16_kernel(const ushort* __restrict__ h16, const int* __restrict__ row_start,
                              const int2* __restrict__ csr2, ushort* __restrict__ aggH16) {
    int w = blockIdx.x * (blockDim.x >> 6) + (threadIdx.x >> 6);
    int lane = threadIdx.x & 63;
    if (w >= NN) return;
    int lo = row_start[w], hi = row_start[w + 1];
    const uint* H = reinterpret_cast<const uint*>(h16);

    if constexpr (DIN == 128) {
        float2 a0 = {0.f,0.f}, a1 = {0.f,0.f}, a2 = {0.f,0.f}, a3 = {0.f,0.f};
        int j = lo;
        while (j < hi) {
            int cnt = hi - j; if (cnt > 64) cnt = 64;
            int myidx = (lane < cnt) ? csr2[j + lane].x : 0;
            int k = 0;
            for (; k + 4 <= cnt; k += 4) {
                int s0 = __shfl(myidx, k);
                int s1 = __shfl(myidx, k + 1);
                int s2 = __shfl(myidx, k + 2);
                int s3 = __shfl(myidx, k + 3);
                float2 v0 = h2f2(H[(size_t)s0 * 64 + lane]);
                float2 v1 = h2f2(H[(size_t)s1 * 64 + lane]);
                float2 v2 = h2f2(H[(size_t)s2 * 64 + lane]);
                float2 v3 = h2f2(H[(size_t)s3 * 64 + lane]);
                a0.x += v0.x; a0.y += v0.y;
                a1.x += v1.x; a1.y += v1.y;
                a2.x += v2.x; a2.y += v2.y;
                a3.x += v3.x; a3.y += v3.y;
            }
            for (; k < cnt; ++k) {
                int s = __shfl(myidx, k);
                float2 v = h2f2(H[(size_t)s * 64 + lane]);
                a0.x += v.x; a0.y += v.y;
            }
            j += cnt;
        }
        a0.x += a1.x; a0.y += a1.y;
        a2.x += a3.x; a2.y += a3.y;
        a0.x += a2.x; a0.y += a2.y;
        reinterpret_cast<uint*>(aggH16)[(size_t)w * 64 + lane] =
            packh2(a0.x * AGG_SCALE, a0.y * AGG_SCALE);
    } else {  // DIN == 64
        int hf = lane >> 5, l32 = lane & 31;
        float2 a0 = {0.f,0.f}, a1 = {0.f,0.f};
        int j = lo;
        while (j < hi) {
            int cnt = hi - j; if (cnt > 64) cnt = 64;
            int myidx = (lane < cnt) ? csr2[j + lane].x : 0;
            int k = 0;
            for (; k + 4 <= cnt; k += 4) {
                int s0 = __shfl(myidx, k + hf);
                int s1 = __shfl(myidx, k + 2 + hf);
                float2 v0 = h2f2(H[(size_t)s0 * 32 + l32]);
                float2 v1 = h2f2(H[(size_t)s1 * 32 + l32]);
                a0.x += v0.x; a0.y += v0.y;
                a1.x += v1.x; a1.y += v1.y;
            }
            for (; k + 2 <= cnt; k += 2) {
                int s = __shfl(myidx, k + hf);
                float2 v = h2f2(H[(size_t)s * 32 + l32]);
                a0.x += v.x; a0.y += v.y;
            }
            if (k < cnt) {
                int s = __shfl(myidx, k);
                if (hf == 0) {
                    float2 v = h2f2(H[(size_t)s * 32 + l32]);
                    a1.x += v.x; a1.y += v.y;
                }
            }
            j += cnt;
        }
        a0.x += a1.x; a0.y += a1.y;
        a0.x += __shfl_xor(a0.x, 32);
        a0.y += __shfl_xor(a0.y, 32);
        if (lane < 32)
            reinterpret_cast<uint*>(aggH16)[(size_t)w * 32 + l32] =
                packh2(a0.x * AGG_SCALE, a0.y * AGG_SCALE);
    }
}

// ---------------------------------------------------------------- weight prep (ALL layers, one dispatch)
// SINGLE fp16 plane per layer, MFMA-FRAGMENT-LINEAR order (proven R12 decode);
// Wm node-rows pre-scaled by W_SCALE (exact pow2).
#define PW_N0 6144       // 64*96
#define PW_N1 20480      // 128*160
#define PW_N2 36864      // 128*288
#define PW_TOTAL (PW_N0 + PW_N1 + 3 * PW_N2)   // 137216
__global__ void prep_w_all(
    const float* __restrict__ Ws0, const float* __restrict__ Wm0, ushort* __restrict__ Wf0,
    const float* __restrict__ Ws1, const float* __restrict__ Wm1, ushort* __restrict__ Wf1,
    const float* __restrict__ Ws2, const float* __restrict__ Wm2, ushort* __restrict__ Wf2,
    const float* __restrict__ Ws3, const float* __restrict__ Wm3, ushort* __restrict__ Wf3,
    const float* __restrict__ Ws4, const float* __restrict__ Wm4, ushort* __restrict__ Wf4) {
    int gid = blockIdx.x * blockDim.x + threadIdx.x;
    if (gid >= PW_TOTAL) return;
    const float *Ws, *Wm; ushort *Wf;
    int DIN, DOUT, lg;
    if (gid < PW_N0) {
        Ws = Ws0; Wm = Wm0; Wf = Wf0; DIN = 32;  DOUT = 64;  lg = gid;
    } else if (gid < PW_N0 + PW_N1) {
        Ws = Ws1; Wm = Wm1; Wf = Wf1; DIN = 64;  DOUT = 128; lg = gid - PW_N0;
    } else if (gid < PW_N0 + PW_N1 + PW_N2) {
        Ws = Ws2; Wm = Wm2; Wf = Wf2; DIN = 128; DOUT = 128; lg = gid - PW_N0 - PW_N1;
    } else if (gid < PW_N0 + PW_N1 + 2 * PW_N2) {
        Ws = Ws3; Wm = Wm3; Wf = Wf3; DIN = 128; DOUT = 128; lg = gid - PW_N0 - PW_N1 - PW_N2;
    } else {
        Ws = Ws4; Wm = Wm4; Wf = Wf4; DIN = 128; DOUT = 128; lg = gid - PW_N0 - PW_N1 - 2 * PW_N2;
    }
    int NSUB = DOUT / 16;
    int j = lg & 7;
    int lane = (lg >> 3) & 63;
    int cs = lg >> 9;
    int c = cs / NSUB, s = cs - c * NSUB;
    int col = s * 16 + (lane & 15);
    int k = c * 32 + (lane >> 4) * 8 + j;
    float v = 0.f;
    if (k < DIN) v = Ws[(size_t)k * DOUT + col];
    else if (k < 2 * DIN) v = Wm[(size_t)(k - DIN) * DOUT + col] * W_SCALE;
    else if (k < 2 * DIN + 8) v = Wm[(size_t)(k - DIN) * DOUT + col];
    Wf[lg] = f2h(v);
}

// ---------------------------------------------------------------- dense MFMA v7 (f16)
// Barrier-free main loop. A-frags: pure uint4 reinterpret of fp16 h/aggH
// (scaled, in range); aggE fp32 -> fp16 in-reg; layer0 x fp32 -> fp16.
// W: single fp16 plane, fragment-linear. ONE mfma_f32_16x16x32_f16 per subtile.
template <int DIN, int DOUT, bool AH16, bool FINAL>
__global__ __launch_bounds__(256) void dense_mfma(
    const float* __restrict__ hF, const ushort* __restrict__ hH,
    const ushort* __restrict__ aggH16, const float* __restrict__ aggE,
    const ushort* __restrict__ Wf, const float* __restrict__ bias,
    ushort* __restrict__ out16, const float* __restrict__ Wc,
    const float* __restrict__ bc, float* __restrict__ outF) {
    constexpr int HCH = DIN / 32;
    constexpr int NCH = 2 * HCH + 1;
    constexpr int NSUB = DOUT / 16;
    constexpr int SB = DOUT + 4;        // bounce stride (floats)

    __shared__ float fs[64 * SB];

    const int t = threadIdx.x;
    const int lane = t & 63, wid = t >> 6;
    const int row0 = blockIdx.x * 64;
    const int rb = wid * 16;
    const int ocol = lane & 15;
    const int rq = lane >> 4;           // k-granule for A; row-quad for C
    const int arow = row0 + rb + ocol;
    const bool rok = arow < NN;

    f32x4 acc[NSUB];
#pragma unroll
    for (int s = 0; s < NSUB; ++s) acc[s] = (f32x4){0.f, 0.f, 0.f, 0.f};

    auto loadA = [&](int c) -> f16x8 {
        uint4 u = {0u, 0u, 0u, 0u};
        if (rok) {
            if (c < HCH) {
                if constexpr (AH16) {
                    u = *reinterpret_cast<const uint4*>(
                        hH + (size_t)arow * DIN + c * 32 + rq * 8);
                } else {
                    const float* p = hF + (size_t)arow * DIN + c * 32 + rq * 8;
                    float4 v0 = *reinterpret_cast<const float4*>(p);
                    float4 v1 = *reinterpret_cast<const float4*>(p + 4);
                    u.x = packh2(v0.x, v0.y); u.y = packh2(v0.z, v0.w);
                    u.z = packh2(v1.x, v1.y); u.w = packh2(v1.z, v1.w);
                }
            } else if (c < 2 * HCH) {
                u = *reinterpret_cast<const uint4*>(
                    aggH16 + (size_t)arow * DIN + (c - HCH) * 32 + rq * 8);
            } else if (rq == 0) {
                const float* p = aggE + (size_t)arow * 8;
                float4 v0 = *reinterpret_cast<const float4*>(p);
                float4 v1 = *reinterpret_cast<const float4*>(p + 4);
                u.x = packh2(v0.x, v0.y); u.y = packh2(v0.z, v0.w);
                u.z = packh2(v1.x, v1.y); u.w = packh2(v1.z, v1.w);
            }
        }
        return __builtin_bit_cast(f16x8, u);
    };

    f16x8 a = loadA(0), a2;

    for (int c = 0; c < NCH; ++c) {
        if (c + 1 < NCH) a2 = loadA(c + 1);        // prefetch flies under MFMAs
        const size_t wbase = ((size_t)(c * NSUB) * 64 + lane) * 8;
#pragma unroll
        for (int s = 0; s < NSUB; ++s) {
            f16x8 w = *reinterpret_cast<const f16x8*>(Wf + wbase + (size_t)s * 512);
            acc[s] = __builtin_amdgcn_mfma_f32_16x16x32_f16(a, w, acc[s], 0, 0, 0);
        }
        if (c + 1 < NCH) a = a2;
    }

    // epilogue: bias+relu into LDS bounce, one barrier
#pragma unroll
    for (int s = 0; s < NSUB; ++s) {
        float bv = bias[s * 16 + ocol];
#pragma unroll
        for (int r = 0; r < 4; ++r) {
            float v = acc[s][r] + bv;
            v = v > 0.f ? v : 0.f;      // relu every layer (incl. feat = relu(h5))
            fs[(rb + rq * 4 + r) * SB + s * 16 + ocol] = v;
        }
    }
    __syncthreads();

    if constexpr (FINAL) {
        // fused readout: 4 threads per row, each dots 32 cols with Wc
        int r = t >> 2, q = t & 3;
        const float* p = fs + r * SB + q * 32;
        const float4* W4 = reinterpret_cast<const float4*>(Wc + q * 32);
        float s = 0.f;
#pragma unroll
        for (int i = 0; i < 8; ++i) {
            float4 wv = W4[i];
            s += p[i * 4 + 0] * wv.x + p[i * 4 + 1] * wv.y
               + p[i * 4 + 2] * wv.z + p[i * 4 + 3] * wv.w;
        }
        s += __shfl_xor(s, 1);
        s += __shfl_xor(s, 2);
        int grow = row0 + r;
        if (q == 0 && grow < NN) outF[grow] = s + bc[0];
    } else {
        for (int i = t; i < 64 * DOUT / 2; i += 256) {
            int r = i / (DOUT / 2), c2 = (i % (DOUT / 2)) * 2;
            int grow = row0 + r;
            if (grow < NN) {
                const float* p = fs + r * SB + c2;
                *reinterpret_cast<uint*>(&out16[(size_t)grow * DOUT + c2]) =
                    packh2(p[0], p[1]);
            }
        }
    }
}

// ---------------------------------------------------------------- launch
extern "C" void kernel_launch(void* const* d_in, const int* in_sizes, int n_in,
                              void* d_out, int out_size, void* d_ws, size_t ws_size,
                              hipStream_t stream) {
    const float* x   = (const float*)d_in[0];
    const float* ea  = (const float*)d_in[1];
    const int*   src = (const int*)d_in[2];
    const int*   dst = (const int*)d_in[3];
    const float* Ws[5]; const float* Wm[5]; const float* bb[5];
    for (int i = 0; i < 5; ++i) {
        Ws[i] = (const float*)d_in[4 + 3 * i];
        Wm[i] = (const float*)d_in[5 + 3 * i];
        bb[i] = (const float*)d_in[6 + 3 * i];
    }
    const float* Wc = (const float*)d_in[19];
    const float* bc = (const float*)d_in[20];
    float* out = (float*)d_out;

    size_t off = 0;
    auto alloc = [&](size_t bytes) {
        void* p = (char*)d_ws + off;
        off += (bytes + 255) & ~(size_t)255;
        return p;
    };
    ushort* aggH16  = (ushort*)alloc((size_t)NN * 128 * 2);
    float* aggE     = (float*)alloc((size_t)NN * 8 * 4);
    ushort* hA16    = (ushort*)alloc((size_t)NN * 128 * 2);
    ushort* hB16    = (ushort*)alloc((size_t)NN * 128 * 2);
    ushort* Wf0     = (ushort*)alloc((size_t)64 * 96 * 2);
    ushort* Wf1     = (ushort*)alloc((size_t)128 * 160 * 2);
    ushort* Wf2     = (ushort*)alloc((size_t)128 * 288 * 2);
    ushort* Wf3     = (ushort*)alloc((size_t)128 * 288 * 2);
    ushort* Wf4     = (ushort*)alloc((size_t)128 * 288 * 2);
    int* deg        = (int*)alloc((size_t)(NN + 1) * 4);
    int* row_start  = (int*)alloc((size_t)(NN + 1) * 4);
    int* cursor     = (int*)alloc((size_t)NN * 4);
    int2* csr2      = (int2*)alloc((size_t)NE * 8);
    int* bsum       = (int*)alloc((size_t)SCAN_NB * 4);
    (void)ws_size; (void)in_sizes; (void)n_in; (void)out_size;

    // CSR build
    zero_int_kernel<<<(NN + 255) / 256, 256, 0, stream>>>(deg, NN);
    deg_kernel<<<(NE + 255) / 256, 256, 0, stream>>>(dst, deg, NE);
    scan1_kernel<<<SCAN_NB, 256, 0, stream>>>(deg, row_start, bsum);
    scan23_kernel<<<SCAN_NB, 256, 0, stream>>>(bsum, row_start, cursor);
    fill_kernel<<<(NE + 255) / 256, 256, 0, stream>>>(src, dst, cursor, csr2, NE);

    agge_kernel<<<(NN + 255) / 256, 256, 0, stream>>>(ea, csr2, row_start, aggE);

    // weight prep (single fp16 plane, all layers, one dispatch)
    prep_w_all<<<(PW_TOTAL + 255) / 256, 256, 0, stream>>>(
        Ws[0], Wm[0], Wf0, Ws[1], Wm[1], Wf1, Ws[2], Wm[2], Wf2,
        Ws[3], Wm[3], Wf3, Ws[4], Wm[4], Wf4);

    const int GRID_W = (NN + 3) / 4;
    const int GRID_D = (NN + 63) / 64;

    // layer 0: 32 -> 64
    aggh32_kernel<<<GRID_W, 256, 0, stream>>>(x, row_start, csr2, aggH16);
    dense_mfma<32, 64, false, false><<<GRID_D, 256, 0, stream>>>(
        x, nullptr, aggH16, aggE, Wf0, bb[0], hA16, nullptr, nullptr, nullptr);
    // layer 1: 64 -> 128
    aggh16_kernel<64><<<GRID_W, 256, 0, stream>>>(hA16, row_start, csr2, aggH16);
    dense_mfma<64, 128, true, false><<<GRID_D, 256, 0, stream>>>(
        nullptr, hA16, aggH16, aggE, Wf1, bb[1], hB16, nullptr, nullptr, nullptr);
    // layer 2
    aggh16_kernel<128><<<GRID_W, 256, 0, stream>>>(hB16, row_start, csr2, aggH16);
    dense_mfma<128, 128, true, false><<<GRID_D, 256, 0, stream>>>(
        nullptr, hB16, aggH16, aggE, Wf2, bb[2], hA16, nullptr, nullptr, nullptr);
    // layer 3
    aggh16_kernel<128><<<GRID_W, 256, 0, stream>>>(hA16, row_start, csr2, aggH16);
    dense_mfma<128, 128, true, false><<<GRID_D, 256, 0, stream>>>(
        nullptr, hA16, aggH16, aggE, Wf3, bb[3], hB16, nullptr, nullptr, nullptr);
    // layer 4 + fused readout
    aggh16_kernel<128><<<GRID_W, 256, 0, stream>>>(hB16, row_start, csr2, aggH16);
    dense_mfma<128, 128, true, true><<<GRID_D, 256, 0, stream>>>(
        nullptr, hB16, aggH16, aggE, Wf4, bb[4], nullptr, Wc, bc, out);
}

// Round 21
// 316.138 us; speedup vs baseline: 1.2262x; 1.0490x over previous
//
#include <hip/hip_runtime.h>
#include <hip/hip_bf16.h>
#include <hip/hip_fp16.h>

#define NN 50000
#define NE 800000
#define SCAN_NB ((NN + 255) / 256)   // 196
#define AGG_SCALE 0.015625f          // 1/64: keeps aggH inside fp16 range
#define W_SCALE   64.0f              // folded into Wm node-block rows (exact)

typedef __attribute__((ext_vector_type(8))) _Float16 f16x8;
typedef __attribute__((ext_vector_type(4))) float f32x4;

__device__ __forceinline__ ushort f2h(float f) {
    __half h = __float2half(f);
    return __builtin_bit_cast(ushort, h);
}
__device__ __forceinline__ uint packh2(float a, float b) {
    return (uint)f2h(a) | ((uint)f2h(b) << 16);
}
__device__ __forceinline__ float2 h2f2(uint u) {
    __half2 h = __builtin_bit_cast(__half2, u);
    return __half22float2(h);
}

// ---------------------------------------------------------------- utilities
__global__ void zero_int_kernel(int* __restrict__ p, int n) {
    int i = blockIdx.x * blockDim.x + threadIdx.x;
    if (i < n) p[i] = 0;
}

// ---------------------------------------------------------------- CSR build
__global__ void deg_kernel(const int* __restrict__ dst, int* __restrict__ deg, int E) {
    int e = blockIdx.x * blockDim.x + threadIdx.x;
    if (e < E) atomicAdd(&deg[dst[e]], 1);
}

__global__ void scan1_kernel(const int* __restrict__ deg, int* __restrict__ pre,
                             int* __restrict__ bsum) {
    __shared__ int sm[256];
    int t = threadIdx.x;
    int i = blockIdx.x * 256 + t;
    int v = (i < NN) ? deg[i] : 0;
    sm[t] = v;
    __syncthreads();
#pragma unroll
    for (int off = 1; off < 256; off <<= 1) {
        int u = (t >= off) ? sm[t - off] : 0;
        __syncthreads();
        sm[t] += u;
        __syncthreads();
    }
    if (i < NN) pre[i] = sm[t] - v;
    if (t == 255) bsum[blockIdx.x] = sm[255];
}

// fused scan2+scan3: each block computes its own bsum prefix (196 values)
__global__ void scan23_kernel(const int* __restrict__ bsum, int* __restrict__ row_start,
                              int* __restrict__ cursor) {
    __shared__ int sm[256];
    int t = threadIdx.x;
    sm[t] = (t < (int)blockIdx.x) ? bsum[t] : 0;   // blockIdx.x < 256
    __syncthreads();
#pragma unroll
    for (int off = 128; off; off >>= 1) {
        if (t < off) sm[t] += sm[t + off];
        __syncthreads();
    }
    int boff = sm[0];
    int i = blockIdx.x * 256 + t;
    if (i < NN) {
        int r = row_start[i] + boff;
        row_start[i] = r;
        cursor[i] = r;
    }
    if (i == 0) row_start[NN] = NE;
}

// fill CSR: single int2 {src, eid} scatter (8B)
__global__ void fill_kernel(const int* __restrict__ src, const int* __restrict__ dst,
                            int* __restrict__ cursor, int2* __restrict__ csr2, int E) {
    int e = blockIdx.x * blockDim.x + threadIdx.x;
    if (e < E) {
        int d = dst[e];
        int p = atomicAdd(&cursor[d], 1);
        csr2[p] = make_int2(src[e], e);
    }
}

// ---------------------------------------------------------------- agg_h layer0 + agg_e (fused)
// half-wave per x-row (32 floats); lanes 0-7 of each half also gather ea[eid]
// (8 floats) for that half's edge. fp32 accum; scaled fp16 aggH out; fp32 aggE out.
__global__ void aggh32_agge_kernel(const float* __restrict__ x, const float* __restrict__ ea,
                                   const int* __restrict__ row_start,
                                   const int2* __restrict__ csr2,
                                   ushort* __restrict__ aggH16, float* __restrict__ aggE) {
    int w = blockIdx.x * (blockDim.x >> 6) + (threadIdx.x >> 6);
    int lane = threadIdx.x & 63;
    if (w >= NN) return;
    int lo = row_start[w], hi = row_start[w + 1];
    int half = lane >> 5;
    int l32 = lane & 31;
    float a0 = 0.f, a1 = 0.f, a2 = 0.f, a3 = 0.f;
    float ae = 0.f;
    int j = lo;
    while (j < hi) {
        int cnt = hi - j; if (cnt > 64) cnt = 64;
        int2 pr = (lane < cnt) ? csr2[j + lane] : make_int2(0, 0);
        int myidx = pr.x, myeid = pr.y;
        int k = 0;
        for (; k + 8 <= cnt; k += 8) {
            int s0 = __shfl(myidx, k + half);
            int s1 = __shfl(myidx, k + 2 + half);
            int s2 = __shfl(myidx, k + 4 + half);
            int s3 = __shfl(myidx, k + 6 + half);
            int e0 = __shfl(myeid, k + half);
            int e1 = __shfl(myeid, k + 2 + half);
            int e2 = __shfl(myeid, k + 4 + half);
            int e3 = __shfl(myeid, k + 6 + half);
            a0 += x[(size_t)s0 * 32 + l32];
            a1 += x[(size_t)s1 * 32 + l32];
            a2 += x[(size_t)s2 * 32 + l32];
            a3 += x[(size_t)s3 * 32 + l32];
            if (l32 < 8) {
                ae += ea[(size_t)e0 * 8 + l32];
                ae += ea[(size_t)e1 * 8 + l32];
                ae += ea[(size_t)e2 * 8 + l32];
                ae += ea[(size_t)e3 * 8 + l32];
            }
        }
        for (; k + 2 <= cnt; k += 2) {
            int s = __shfl(myidx, k + half);
            int e = __shfl(myeid, k + half);
            a0 += x[(size_t)s * 32 + l32];
            if (l32 < 8) ae += ea[(size_t)e * 8 + l32];
        }
        if (k < cnt) {
            int s = __shfl(myidx, k);
            int e = __shfl(myeid, k);
            if (half == 0) {
                a1 += x[(size_t)s * 32 + l32];
                if (l32 < 8) ae += ea[(size_t)e * 8 + l32];
            }
        }
        j += cnt;
    }
    a0 = (a0 + a1) + (a2 + a3);
    a0 += __shfl_xor(a0, 32);
    ae += __shfl_xor(ae, 32);
    a0 *= AGG_SCALE;
    float an = __shfl_down(a0, 1);
    if (lane < 32 && (lane & 1) == 0)
        reinterpret_cast<uint*>(aggH16)[(size_t)w * 16 + (lane >> 1)] = packh2(a0, an);
    if (lane < 8) aggE[(size_t)w * 8 + lane] = ae;
}

// ---------------------------------------------------------------- agg_h fp16 gather, scaled fp16 out
template <int DIN>
__global__ void aggh16_kernel(const ushort* __restrict__ h16, const int* __restrict__ row_start,
                              const int2* __restrict__ csr2, ushort* __restrict__ aggH16) {
    int w = blockIdx.x * (blockDim.x >> 6) + (threadIdx.x >> 6);
    int lane = threadIdx.x & 63;
    if (w >= NN) return;
    int lo = row_start[w], hi = row_start[w + 1];

    if constexpr (DIN == 128) {
        // half-wave per row (uint2 = 8B/lane); 2 rows/pass x 4-deep = 8 rows in flight
        const uint2* H2 = reinterpret_cast<const uint2*>(h16);
        int hf = lane >> 5, l32 = lane & 31;
        float b0[4] = {0.f,0.f,0.f,0.f}, b1[4] = {0.f,0.f,0.f,0.f};
        float b2[4] = {0.f,0.f,0.f,0.f}, b3[4] = {0.f,0.f,0.f,0.f};
        int j = lo;
        while (j < hi) {
            int cnt = hi - j; if (cnt > 64) cnt = 64;
            int myidx = (lane < cnt) ? csr2[j + lane].x : 0;
            int k = 0;
            for (; k + 8 <= cnt; k += 8) {
                int s0 = __shfl(myidx, k + hf);
                int s1 = __shfl(myidx, k + 2 + hf);
                int s2 = __shfl(myidx, k + 4 + hf);
                int s3 = __shfl(myidx, k + 6 + hf);
                uint2 u0 = H2[(size_t)s0 * 32 + l32];
                uint2 u1 = H2[(size_t)s1 * 32 + l32];
                uint2 u2 = H2[(size_t)s2 * 32 + l32];
                uint2 u3 = H2[(size_t)s3 * 32 + l32];
                float2 p;
                p = h2f2(u0.x); b0[0] += p.x; b0[1] += p.y;
                p = h2f2(u0.y); b0[2] += p.x; b0[3] += p.y;
                p = h2f2(u1.x); b1[0] += p.x; b1[1] += p.y;
                p = h2f2(u1.y); b1[2] += p.x; b1[3] += p.y;
                p = h2f2(u2.x); b2[0] += p.x; b2[1] += p.y;
                p = h2f2(u2.y); b2[2] += p.x; b2[3] += p.y;
                p = h2f2(u3.x); b3[0] += p.x; b3[1] += p.y;
                p = h2f2(u3.y); b3[2] += p.x; b3[3] += p.y;
            }
            for (; k + 2 <= cnt; k += 2) {
                int s = __shfl(myidx, k + hf);
                uint2 u = H2[(size_t)s * 32 + l32];
                float2 p;
                p = h2f2(u.x); b0[0] += p.x; b0[1] += p.y;
                p = h2f2(u.y); b0[2] += p.x; b0[3] += p.y;
            }
            if (k < cnt) {
                int s = __shfl(myidx, k);
                if (hf == 0) {
                    uint2 u = H2[(size_t)s * 32 + l32];
                    float2 p;
                    p = h2f2(u.x); b1[0] += p.x; b1[1] += p.y;
                    p = h2f2(u.y); b1[2] += p.x; b1[3] += p.y;
                }
            }
            j += cnt;
        }
        float a0 = (b0[0] + b1[0]) + (b2[0] + b3[0]);
        float a1 = (b0[1] + b1[1]) + (b2[1] + b3[1]);
        float a2 = (b0[2] + b1[2]) + (b2[2] + b3[2]);
        float a3 = (b0[3] + b1[3]) + (b2[3] + b3[3]);
        a0 += __shfl_xor(a0, 32);
        a1 += __shfl_xor(a1, 32);
        a2 += __shfl_xor(a2, 32);
        a3 += __shfl_xor(a3, 32);
        if (lane < 32) {
            uint2 o;
            o.x = packh2(a0 * AGG_SCALE, a1 * AGG_SCALE);
            o.y = packh2(a2 * AGG_SCALE, a3 * AGG_SCALE);
            reinterpret_cast<uint2*>(aggH16)[(size_t)w * 32 + l32] = o;
        }
    } else {  // DIN == 64
        const uint* H = reinterpret_cast<const uint*>(h16);
        int hf = lane >> 5, l32 = lane & 31;
        float2 a0 = {0.f,0.f}, a1 = {0.f,0.f};
        int j = lo;
        while (j < hi) {
            int cnt = hi - j; if (cnt > 64) cnt = 64;
            int myidx = (lane < cnt) ? csr2[j + lane].x : 0;
            int k = 0;
            for (; k + 4 <= cnt; k += 4) {
                int s0 = __shfl(myidx, k + hf);
                int s1 = __shfl(myidx, k + 2 + hf);
                float2 v0 = h2f2(H[(size_t)s0 * 32 + l32]);
                float2 v1 = h2f2(H[(size_t)s1 * 32 + l32]);
                a0.x += v0.x; a0.y += v0.y;
                a1.x += v1.x; a1.y += v1.y;
            }
            for (; k + 2 <= cnt; k += 2) {
                int s = __shfl(myidx, k + hf);
                float2 v = h2f2(H[(size_t)s * 32 + l32]);
                a0.x += v.x; a0.y += v.y;
            }
            if (k < cnt) {
                int s = __shfl(myidx, k);
                if (hf == 0) {
                    float2 v = h2f2(H[(size_t)s * 32 + l32]);
                    a1.x += v.x; a1.y += v.y;
                }
            }
            j += cnt;
        }
        a0.x += a1.x; a0.y += a1.y;
        a0.x += __shfl_xor(a0.x, 32);
        a0.y += __shfl_xor(a0.y, 32);
        if (lane < 32)
            reinterpret_cast<uint*>(aggH16)[(size_t)w * 32 + l32] =
                packh2(a0.x * AGG_SCALE, a0.y * AGG_SCALE);
    }
}

// ---------------------------------------------------------------- weight prep (ALL layers, one dispatch)
#define PW_N0 6144       // 64*96
#define PW_N1 20480      // 128*160
#define PW_N2 36864      // 128*288
#define PW_TOTAL (PW_N0 + PW_N1 + 3 * PW_N2)   // 137216
__global__ void prep_w_all(
    const float* __restrict__ Ws0, const float* __restrict__ Wm0, ushort* __restrict__ Wf0,
    const float* __restrict__ Ws1, const float* __restrict__ Wm1, ushort* __restrict__ Wf1,
    const float* __restrict__ Ws2, const float* __restrict__ Wm2, ushort* __restrict__ Wf2,
    const float* __restrict__ Ws3, const float* __restrict__ Wm3, ushort* __restrict__ Wf3,
    const float* __restrict__ Ws4, const float* __restrict__ Wm4, ushort* __restrict__ Wf4) {
    int gid = blockIdx.x * blockDim.x + threadIdx.x;
    if (gid >= PW_TOTAL) return;
    const float *Ws, *Wm; ushort *Wf;
    int DIN, DOUT, lg;
    if (gid < PW_N0) {
        Ws = Ws0; Wm = Wm0; Wf = Wf0; DIN = 32;  DOUT = 64;  lg = gid;
    } else if (gid < PW_N0 + PW_N1) {
        Ws = Ws1; Wm = Wm1; Wf = Wf1; DIN = 64;  DOUT = 128; lg = gid - PW_N0;
    } else if (gid < PW_N0 + PW_N1 + PW_N2) {
        Ws = Ws2; Wm = Wm2; Wf = Wf2; DIN = 128; DOUT = 128; lg = gid - PW_N0 - PW_N1;
    } else if (gid < PW_N0 + PW_N1 + 2 * PW_N2) {
        Ws = Ws3; Wm = Wm3; Wf = Wf3; DIN = 128; DOUT = 128; lg = gid - PW_N0 - PW_N1 - PW_N2;
    } else {
        Ws = Ws4; Wm = Wm4; Wf = Wf4; DIN = 128; DOUT = 128; lg = gid - PW_N0 - PW_N1 - 2 * PW_N2;
    }
    int NSUB = DOUT / 16;
    int j = lg & 7;
    int lane = (lg >> 3) & 63;
    int cs = lg >> 9;
    int c = cs / NSUB, s = cs - c * NSUB;
    int col = s * 16 + (lane & 15);
    int k = c * 32 + (lane >> 4) * 8 + j;
    float v = 0.f;
    if (k < DIN) v = Ws[(size_t)k * DOUT + col];
    else if (k < 2 * DIN) v = Wm[(size_t)(k - DIN) * DOUT + col] * W_SCALE;
    else if (k < 2 * DIN + 8) v = Wm[(size_t)(k - DIN) * DOUT + col];
    Wf[lg] = f2h(v);
}

// ---------------------------------------------------------------- dense MFMA v7 (f16)
template <int DIN, int DOUT, bool AH16, bool FINAL>
__global__ __launch_bounds__(256) void dense_mfma(
    const float* __restrict__ hF, const ushort* __restrict__ hH,
    const ushort* __restrict__ aggH16, const float* __restrict__ aggE,
    const ushort* __restrict__ Wf, const float* __restrict__ bias,
    ushort* __restrict__ out16, const float* __restrict__ Wc,
    const float* __restrict__ bc, float* __restrict__ outF) {
    constexpr int HCH = DIN / 32;
    constexpr int NCH = 2 * HCH + 1;
    constexpr int NSUB = DOUT / 16;
    constexpr int SB = DOUT + 4;        // bounce stride (floats)

    __shared__ float fs[64 * SB];

    const int t = threadIdx.x;
    const int lane = t & 63, wid = t >> 6;
    const int row0 = blockIdx.x * 64;
    const int rb = wid * 16;
    const int ocol = lane & 15;
    const int rq = lane >> 4;           // k-granule for A; row-quad for C
    const int arow = row0 + rb + ocol;
    const bool rok = arow < NN;

    f32x4 acc[NSUB];
#pragma unroll
    for (int s = 0; s < NSUB; ++s) acc[s] = (f32x4){0.f, 0.f, 0.f, 0.f};

    auto loadA = [&](int c) -> f16x8 {
        uint4 u = {0u, 0u, 0u, 0u};
        if (rok) {
            if (c < HCH) {
                if constexpr (AH16) {
                    u = *reinterpret_cast<const uint4*>(
                        hH + (size_t)arow * DIN + c * 32 + rq * 8);
                } else {
                    const float* p = hF + (size_t)arow * DIN + c * 32 + rq * 8;
                    float4 v0 = *reinterpret_cast<const float4*>(p);
                    float4 v1 = *reinterpret_cast<const float4*>(p + 4);
                    u.x = packh2(v0.x, v0.y); u.y = packh2(v0.z, v0.w);
                    u.z = packh2(v1.x, v1.y); u.w = packh2(v1.z, v1.w);
                }
            } else if (c < 2 * HCH) {
                u = *reinterpret_cast<const uint4*>(
                    aggH16 + (size_t)arow * DIN + (c - HCH) * 32 + rq * 8);
            } else if (rq == 0) {
                const float* p = aggE + (size_t)arow * 8;
                float4 v0 = *reinterpret_cast<const float4*>(p);
                float4 v1 = *reinterpret_cast<const float4*>(p + 4);
                u.x = packh2(v0.x, v0.y); u.y = packh2(v0.z, v0.w);
                u.z = packh2(v1.x, v1.y); u.w = packh2(v1.z, v1.w);
            }
        }
        return __builtin_bit_cast(f16x8, u);
    };

    f16x8 a = loadA(0), a2;

    for (int c = 0; c < NCH; ++c) {
        if (c + 1 < NCH) a2 = loadA(c + 1);        // prefetch flies under MFMAs
        const size_t wbase = ((size_t)(c * NSUB) * 64 + lane) * 8;
#pragma unroll
        for (int s = 0; s < NSUB; ++s) {
            f16x8 w = *reinterpret_cast<const f16x8*>(Wf + wbase + (size_t)s * 512);
            acc[s] = __builtin_amdgcn_mfma_f32_16x16x32_f16(a, w, acc[s], 0, 0, 0);
        }
        if (c + 1 < NCH) a = a2;
    }

    // epilogue: bias+relu into LDS bounce, one barrier
#pragma unroll
    for (int s = 0; s < NSUB; ++s) {
        float bv = bias[s * 16 + ocol];
#pragma unroll
        for (int r = 0; r < 4; ++r) {
            float v = acc[s][r] + bv;
            v = v > 0.f ? v : 0.f;      // relu every layer (incl. feat = relu(h5))
            fs[(rb + rq * 4 + r) * SB + s * 16 + ocol] = v;
        }
    }
    __syncthreads();

    if constexpr (FINAL) {
        int r = t >> 2, q = t & 3;
        const float* p = fs + r * SB + q * 32;
        const float4* W4 = reinterpret_cast<const float4*>(Wc + q * 32);
        float s = 0.f;
#pragma unroll
        for (int i = 0; i < 8; ++i) {
            float4 wv = W4[i];
            s += p[i * 4 + 0] * wv.x + p[i * 4 + 1] * wv.y
               + p[i * 4 + 2] * wv.z + p[i * 4 + 3] * wv.w;
        }
        s += __shfl_xor(s, 1);
        s += __shfl_xor(s, 2);
        int grow = row0 + r;
        if (q == 0 && grow < NN) outF[grow] = s + bc[0];
    } else {
        for (int i = t; i < 64 * DOUT / 2; i += 256) {
            int r = i / (DOUT / 2), c2 = (i % (DOUT / 2)) * 2;
            int grow = row0 + r;
            if (grow < NN) {
                const float* p = fs + r * SB + c2;
                *reinterpret_cast<uint*>(&out16[(size_t)grow * DOUT + c2]) =
                    packh2(p[0], p[1]);
            }
        }
    }
}

// ---------------------------------------------------------------- launch
extern "C" void kernel_launch(void* const* d_in, const int* in_sizes, int n_in,
                              void* d_out, int out_size, void* d_ws, size_t ws_size,
                              hipStream_t stream) {
    const float* x   = (const float*)d_in[0];
    const float* ea  = (const float*)d_in[1];
    const int*   src = (const int*)d_in[2];
    const int*   dst = (const int*)d_in[3];
    const float* Ws[5]; const float* Wm[5]; const float* bb[5];
    for (int i = 0; i < 5; ++i) {
        Ws[i] = (const float*)d_in[4 + 3 * i];
        Wm[i] = (const float*)d_in[5 + 3 * i];
        bb[i] = (const float*)d_in[6 + 3 * i];
    }
    const float* Wc = (const float*)d_in[19];
    const float* bc = (const float*)d_in[20];
    float* out = (float*)d_out;

    size_t off = 0;
    auto alloc = [&](size_t bytes) {
        void* p = (char*)d_ws + off;
        off += (bytes + 255) & ~(size_t)255;
        return p;
    };
    ushort* aggH16  = (ushort*)alloc((size_t)NN * 128 * 2);
    float* aggE     = (float*)alloc((size_t)NN * 8 * 4);
    ushort* hA16    = (ushort*)alloc((size_t)NN * 128 * 2);
    ushort* hB16    = (ushort*)alloc((size_t)NN * 128 * 2);
    ushort* Wf0     = (ushort*)alloc((size_t)64 * 96 * 2);
    ushort* Wf1     = (ushort*)alloc((size_t)128 * 160 * 2);
    ushort* Wf2     = (ushort*)alloc((size_t)128 * 288 * 2);
    ushort* Wf3     = (ushort*)alloc((size_t)128 * 288 * 2);
    ushort* Wf4     = (ushort*)alloc((size_t)128 * 288 * 2);
    int* deg        = (int*)alloc((size_t)(NN + 1) * 4);
    int* row_start  = (int*)alloc((size_t)(NN + 1) * 4);
    int* cursor     = (int*)alloc((size_t)NN * 4);
    int2* csr2      = (int2*)alloc((size_t)NE * 8);
    int* bsum       = (int*)alloc((size_t)SCAN_NB * 4);
    (void)ws_size; (void)in_sizes; (void)n_in; (void)out_size;

    // CSR build
    zero_int_kernel<<<(NN + 255) / 256, 256, 0, stream>>>(deg, NN);
    deg_kernel<<<(NE + 255) / 256, 256, 0, stream>>>(dst, deg, NE);
    scan1_kernel<<<SCAN_NB, 256, 0, stream>>>(deg, row_start, bsum);
    scan23_kernel<<<SCAN_NB, 256, 0, stream>>>(bsum, row_start, cursor);
    fill_kernel<<<(NE + 255) / 256, 256, 0, stream>>>(src, dst, cursor, csr2, NE);

    // weight prep (single fp16 plane, all layers, one dispatch)
    prep_w_all<<<(PW_TOTAL + 255) / 256, 256, 0, stream>>>(
        Ws[0], Wm[0], Wf0, Ws[1], Wm[1], Wf1, Ws[2], Wm[2], Wf2,
        Ws[3], Wm[3], Wf3, Ws[4], Wm[4], Wf4);

    const int GRID_W = (NN + 3) / 4;
    const int GRID_D = (NN + 63) / 64;

    // layer 0: 32 -> 64 (fused x-gather + aggE)
    aggh32_agge_kernel<<<GRID_W, 256, 0, stream>>>(x, ea, row_start, csr2, aggH16, aggE);
    dense_mfma<32, 64, false, false><<<GRID_D, 256, 0, stream>>>(
        x, nullptr, aggH16, aggE, Wf0, bb[0], hA16, nullptr, nullptr, nullptr);
    // layer 1: 64 -> 128
    aggh16_kernel<64><<<GRID_W, 256, 0, stream>>>(hA16, row_start, csr2, aggH16);
    dense_mfma<64, 128, true, false><<<GRID_D, 256, 0, stream>>>(
        nullptr, hA16, aggH16, aggE, Wf1, bb[1], hB16, nullptr, nullptr, nullptr);
    // layer 2
    aggh16_kernel<128><<<GRID_W, 256, 0, stream>>>(hB16, row_start, csr2, aggH16);
    dense_mfma<128, 128, true, false><<<GRID_D, 256, 0, stream>>>(
        nullptr, hB16, aggH16, aggE, Wf2, bb[2], hA16, nullptr, nullptr, nullptr);
    // layer 3
    aggh16_kernel<128><<<GRID_W, 256, 0, stream>>>(hA16, row_start, csr2, aggH16);
    dense_mfma<128, 128, true, false><<<GRID_D, 256, 0, stream>>>(
        nullptr, hA16, aggH16, aggE, Wf3, bb[3], hB16, nullptr, nullptr, nullptr);
    // layer 4 + fused readout
    aggh16_kernel<128><<<GRID_W, 256, 0, stream>>>(hB16, row_start, csr2, aggH16);
    dense_mfma<128, 128, true, true><<<GRID_D, 256, 0, stream>>>(
        nullptr, hB16, aggH16, aggE, Wf4, bb[4], nullptr, Wc, bc, out);
}